// Round 1
// baseline (255.921 us; speedup 1.0000x reference)
//
#include <hip/hip_runtime.h>
#include <math.h>

#define NMESH 120
#define NKZ 61            // rfft half-spectrum along z
#define NTOT (120*120*120)
#define ALPHA_C 1.0

#define TILE 12           // mesh cells per tile per dim
#define NTPD 10           // tiles per dim
#define NTILE 1000
#define FP 17             // footprint per dim: TILE + 5
#define FPCELLS (FP*FP*FP)   // 4913
#define FPSTRIDE 4928        // padded tile stride (buf layout)
#define SA 292               // LDS accS a-stride: banks (4a+17b)%32 -> max 2-way (free)
#define SACC 4961            // accS size (single shared copy, ds_add_f32 accumulation)
#define CAP 256              // bucket capacity (Poisson(100): overflow ~1e-40)

#define YCH 12            // y-lines per fft_z block (1200 blocks)
#define XCH 4             // x per fft_y block / ky per fft_x block
#define YROW 137          // per-line Y storage: 8 rows * 17 + 1 pad (float2)

#define NSLOT 64          // accumulator slots (64B apart)
#define SLOTSTRIDE 8      // doubles per slot

// ---- workspace layout (bytes) ----
// [0, 4096)      : double ekslots[64*8]
// [4096, 8192)   : double qslots [64*8]
// [8192, 12288)  : double q2slots[64*8]
// [115264, +19712000)  : float buf[1000][4928] tile footprints
// [19827264, +7027200) : float2 C1[x][kz][y]
//    counts + CAP-padded sorted atoms ALIAS the C1 region (dead before fft_z writes C1)
// C2[kz][ky][x] ALIASES buf (buf dead after fft_z)
#define EK_OFF      0
#define Q_OFF       4096
#define Q2_OFF      8192
#define BUF_OFF     115264
#define C1_OFF      19827264
#define C2_OFF      115264
#define COUNTS_OFF  C1_OFF
#define SORTED_OFF  (C1_OFF + 4096)

__device__ inline void inv3(const float* b, float* ib) {
    float a00=b[0],a01=b[1],a02=b[2],a10=b[3],a11=b[4],a12=b[5],a20=b[6],a21=b[7],a22=b[8];
    float c00 =  a11*a22 - a12*a21;
    float c01 = -(a10*a22 - a12*a20);
    float c02 =  a10*a21 - a11*a20;
    float c10 = -(a01*a22 - a02*a21);
    float c11 =  a00*a22 - a02*a20;
    float c12 = -(a00*a21 - a01*a20);
    float c20 =  a01*a12 - a02*a11;
    float c21 = -(a00*a12 - a02*a10);
    float c22 =  a00*a11 - a01*a10;
    float det = a00*c00 + a01*c01 + a02*c02;
    float inv = 1.0f/det;
    ib[0]=c00*inv; ib[1]=c10*inv; ib[2]=c20*inv;
    ib[3]=c01*inv; ib[4]=c11*inv; ib[5]=c21*inv;
    ib[6]=c02*inv; ib[7]=c12*inv; ib[8]=c22*inv;
}

__device__ inline void atom_pos(const float* __restrict__ box, float c0, float c1, float c2,
                                float* p) {
    float ib[9]; inv3(box, ib);
    #pragma unroll
    for (int d=0; d<3; ++d)
        p[d] = (c0*ib[0+d] + c1*ib[3+d] + c2*ib[6+d]) * 120.0f;
}

__device__ inline int wrap120(int i) { return ((i % 120) + 120) % 120; }

// order-6 Lagrange weights; x = pos - (floor(pos)+0.5)
__device__ inline void lag6(float x, float* w) {
    float df[6];
    #pragma unroll
    for (int k=0;k<6;++k) df[k] = x - ((float)k - 2.5f);
    w[0] = df[1]*df[2]*df[3]*df[4]*df[5] * (-1.0f/120.0f);
    w[1] = df[0]*df[2]*df[3]*df[4]*df[5] * ( 1.0f/24.0f);
    w[2] = df[0]*df[1]*df[3]*df[4]*df[5] * (-1.0f/12.0f);
    w[3] = df[0]*df[1]*df[2]*df[4]*df[5] * ( 1.0f/12.0f);
    w[4] = df[0]*df[1]*df[2]*df[3]*df[5] * (-1.0f/24.0f);
    w[5] = df[0]*df[1]*df[2]*df[3]*df[4] * ( 1.0f/120.0f);
}

// per-dim halo decomposition: cell c -> up to 2 (tile, local) pairs
__device__ inline int halo_pairs(int c, int* t, int* l) {
    int r = c % 12, ti = c / 12, n = 0;
    t[n] = ti;          l[n] = r + 2;  n++;
    if (r < 3)  { t[n] = (ti+9)%10; l[n] = r + 14; n++; }
    if (r >= 10){ t[n] = (ti+1)%10; l[n] = r - 10; n++; }
    return n;
}

// 8-point DFT, complex in (m-order), complex out (k-order). W8 = e^{-2pi i/8}.
__device__ inline void dft8(const float2* xin, float2* Y) {
    const float S = 0.70710678118654752f;
    float2 a=xin[0], b=xin[2], c=xin[4], d=xin[6];
    float s02r=a.x+c.x, s02i=a.y+c.y, d02r=a.x-c.x, d02i=a.y-c.y;
    float s13r=b.x+d.x, s13i=b.y+d.y, d13r=b.x-d.x, d13i=b.y-d.y;
    float2 E0 = make_float2(s02r+s13r, s02i+s13i);
    float2 E1 = make_float2(d02r+d13i, d02i-d13r);   // d02 - i*d13
    float2 E2 = make_float2(s02r-s13r, s02i-s13i);
    float2 E3 = make_float2(d02r-d13i, d02i+d13r);
    a=xin[1]; b=xin[3]; c=xin[5]; d=xin[7];
    s02r=a.x+c.x; s02i=a.y+c.y; d02r=a.x-c.x; d02i=a.y-c.y;
    s13r=b.x+d.x; s13i=b.y+d.y; d13r=b.x-d.x; d13i=b.y-d.y;
    float2 O0 = make_float2(s02r+s13r, s02i+s13i);
    float2 O1 = make_float2(d02r+d13i, d02i-d13r);
    float2 O2 = make_float2(s02r-s13r, s02i-s13i);
    float2 O3 = make_float2(d02r-d13i, d02i+d13r);
    float t1r = S*(O1.x + O1.y), t1i = S*(O1.y - O1.x);   // W8^1 * O1
    float t2r = O2.y,            t2i = -O2.x;             // W8^2 = -i
    float t3r = S*(O3.y - O3.x), t3i = -S*(O3.x + O3.y);  // W8^3
    Y[0] = make_float2(E0.x + O0.x, E0.y + O0.y);
    Y[4] = make_float2(E0.x - O0.x, E0.y - O0.y);
    Y[1] = make_float2(E1.x + t1r,  E1.y + t1i);
    Y[5] = make_float2(E1.x - t1r,  E1.y - t1i);
    Y[2] = make_float2(E2.x + t2r,  E2.y + t2i);
    Y[6] = make_float2(E2.x - t2r,  E2.y - t2i);
    Y[3] = make_float2(E3.x + t3r,  E3.y + t3i);
    Y[7] = make_float2(E3.x - t3r,  E3.y - t3i);
}

__global__ void init_kernel(int* __restrict__ counts, double* __restrict__ slots) {
    int idx = threadIdx.x;
    for (int i = idx; i < 3*NSLOT*SLOTSTRIDE; i += 1024) slots[i] = 0.0;
    for (int i = idx; i < NTILE; i += 1024) counts[i] = 0;
}

// one-pass bucket scatter + sum(q) + sum(q^2) into per-slot accumulators
__global__ void scatter_q_kernel(const float* __restrict__ coords,
                                 const float* __restrict__ box,
                                 const float* __restrict__ charges,
                                 int* __restrict__ counts,
                                 float4* __restrict__ sorted,
                                 double* __restrict__ qslots,
                                 double* __restrict__ q2slots, int n) {
    int i = blockIdx.x*blockDim.x + threadIdx.x;
    float v = 0.f, v2 = 0.f;
    if (i < n) {
        float p[3]; atom_pos(box, coords[3*i], coords[3*i+1], coords[3*i+2], p);
        float q = charges[i];
        v = q; v2 = q*q;
        int t[3];
        #pragma unroll
        for (int d=0; d<3; ++d) t[d] = wrap120((int)floorf(p[d])) / TILE;
        int tile = (t[0]*NTPD + t[1])*NTPD + t[2];
        int idx = atomicAdd(&counts[tile], 1);
        if (idx < CAP) sorted[tile*CAP + idx] = make_float4(p[0], p[1], p[2], q);
    }
    #pragma unroll
    for (int o=32;o>0;o>>=1) { v += __shfl_down(v,o,64); v2 += __shfl_down(v2,o,64); }
    __shared__ float s1[4], s2[4];
    int lane = threadIdx.x & 63, w = threadIdx.x >> 6;
    if (lane==0) { s1[w]=v; s2[w]=v2; }
    __syncthreads();
    if (threadIdx.x==0) {
        for (int j=1;j<4;j++) { v += s1[j]; v2 += s2[j]; }
        int slot = (blockIdx.x & (NSLOT-1)) * SLOTSTRIDE;
        atomicAdd(&qslots[slot],  (double)v);
        atomicAdd(&q2slots[slot], (double)v2);
    }
}

// FOUR waves per tile; single shared accS, fire-and-forget ds_add_f32 atomics.
// Work flattened over (atom, a, b) items so all 64 lanes are active
// (previous version: 36/64 lanes + read-modify-write chain with per-atom
//  lgkmcnt stalls; atomics remove the dependency chain entirely).
__global__ void __launch_bounds__(256)
spread_tile_kernel(const float4* __restrict__ sorted,
                   const int* __restrict__ counts,
                   float* __restrict__ buf) {
    int tile = blockIdx.x;
    int tx = tile / (NTPD*NTPD);
    int rem = tile - tx*NTPD*NTPD;
    int ty = rem / NTPD;
    int tz = rem - ty*NTPD;
    int bx = tx*TILE, by = ty*TILE, bz = tz*TILE;

    __shared__ float accS[SACC];
    __shared__ float W[256][18];
    __shared__ int   baseS[256];

    int tid = threadIdx.x;
    for (int i = tid; i < SACC; i += 256) accS[i] = 0.f;

    int cntT = min(counts[tile], CAP);
    const float4* src = sorted + tile*CAP;

    for (int start = 0; start < cntT; start += 256) {
        int my = start + tid;
        if (my < cntT) {
            float4 s = src[my];
            float fx = floorf(s.x);
            float wx[6]; lag6(s.x - (fx + 0.5f), wx);
            float fy = floorf(s.y);
            float wy[6]; lag6(s.y - (fy + 0.5f), wy);
            float fz = floorf(s.z);
            float wz[6]; lag6(s.z - (fz + 0.5f), wz);
            int lx = wrap120((int)fx) - bx;
            int ly = wrap120((int)fy) - by;
            int lz = wrap120((int)fz) - bz;
            baseS[tid] = lx*SA + ly*FP + lz;
            #pragma unroll
            for (int k=0;k<6;++k) {
                W[tid][k]    = wx[k]*s.w;
                W[tid][6+k]  = wy[k];
                W[tid][12+k] = wz[k];
            }
        }
        __syncthreads();
        int jn = cntT - start;
        jn = (jn > 256) ? 256 : jn;
        int nitems = jn * 36;
        for (int it = tid; it < nitems; it += 256) {
            int row = it / 36;
            int ab  = it - row*36;
            int a   = ab / 6;
            int b   = ab - a*6;
            float w2 = W[row][a] * W[row][6+b];
            int ad = baseS[row] + a*SA + b*FP;
            #pragma unroll
            for (int c=0;c<6;++c)
                atomicAdd(&accS[ad + c], w2 * W[row][12+c]);
        }
        __syncthreads();
    }

    for (int i = tid; i < FPCELLS; i += 256) {
        int lx = i / (FP*FP);
        int r  = i - lx*FP*FP;
        int ly = r / FP;
        int lz = r - ly*FP;
        int ai = lx*SA + ly*FP + lz;
        buf[(size_t)tile * FPSTRIDE + i] = accS[ai];
    }
}

// ---- radix-8 decimated 120-point DFT inner loop ----
// X[k] = sum_{j<15} Y[k&7][j] * W120^{k*j};  3 strands (j mod 3) for ILP.
#define DFT15_BODY(Yp, kfreq, RE, IM)                                        \
    float w1r, w1i;                                                          \
    __sincosf(-0.052359877559829887f * (float)(kfreq), &w1i, &w1r);          \
    float w2r = w1r*w1r - w1i*w1i, w2i = 2.f*w1r*w1i;                        \
    float w3r = w2r*w1r - w2i*w1i, w3i = w2r*w1i + w2i*w1r;                  \
    float ar=1.f, ai=0.f, br=w1r, bi=w1i, cr=w2r, ci=w2i;                    \
    float r0_=0.f,i0_=0.f,r1_=0.f,i1_=0.f,r2_=0.f,i2_=0.f;                   \
    _Pragma("unroll")                                                        \
    for (int s_=0;s_<5;++s_) {                                               \
        float2 ya = (Yp)[3*s_], yb = (Yp)[3*s_+1], yc = (Yp)[3*s_+2];        \
        r0_ = fmaf(ya.x, ar, fmaf(-ya.y, ai, r0_));                          \
        i0_ = fmaf(ya.x, ai, fmaf( ya.y, ar, i0_));                          \
        r1_ = fmaf(yb.x, br, fmaf(-yb.y, bi, r1_));                          \
        i1_ = fmaf(yb.x, bi, fmaf( yb.y, br, i1_));                          \
        r2_ = fmaf(yc.x, cr, fmaf(-yc.y, ci, r2_));                          \
        i2_ = fmaf(yc.x, ci, fmaf( yc.y, cr, i2_));                          \
        float n_;                                                            \
        n_ = ar*w3r - ai*w3i; ai = ar*w3i + ai*w3r; ar = n_;                 \
        n_ = br*w3r - bi*w3i; bi = br*w3i + bi*w3r; br = n_;                 \
        n_ = cr*w3r - ci*w3i; ci = cr*w3i + ci*w3r; cr = n_;                 \
    }                                                                        \
    float RE = (r0_+r1_)+r2_, IM = (i0_+i1_)+i2_;

// stage 1: halo-gather + rfft along z (radix-8 pre-combine). out C1[x][kz][y].
__global__ void __launch_bounds__(256)
fft_z_kernel(const float* __restrict__ buf,
             float2* __restrict__ C1) {
    int x  = blockIdx.x / 10;
    int y0 = (blockIdx.x - x*10) * YCH;
    __shared__ float  lin[YCH][121];
    __shared__ float2 Ys[YCH][YROW];    // per line: 8 rows * 17 (+1 pad)

    int txA[2], lxA[2];
    int nx = halo_pairs(x, txA, lxA);

    for (int i = threadIdx.x; i < YCH*120; i += 256) {
        int yl = i / 120, z = i - yl*120;
        int tyA[2], lyA[2]; int ny = halo_pairs(y0 + yl, tyA, lyA);
        int tzA[2], lzA[2]; int nz = halo_pairs(z, tzA, lzA);
        float s = 0.f;
        for (int ii=0; ii<nx; ++ii)
            for (int jj=0; jj<ny; ++jj)
                for (int kk=0; kk<nz; ++kk) {
                    int tile = (txA[ii]*NTPD + tyA[jj])*NTPD + tzA[kk];
                    int cell = (lxA[ii]*FP + lyA[jj])*FP + lzA[kk];
                    s += buf[(size_t)tile*FPSTRIDE + cell];
                }
        lin[yl][z] = s;
    }
    __syncthreads();
    // radix-8 combine: z = 15m + j ; Y[r][j] = sum_m x W8^{rm}
    for (int t = threadIdx.x; t < YCH*15; t += 256) {
        int yl = t / 15, j = t - (t/15)*15;
        float2 xin[8], Yo[8];
        #pragma unroll
        for (int m=0;m<8;++m) xin[m] = make_float2(lin[yl][15*m+j], 0.f);
        dft8(xin, Yo);
        #pragma unroll
        for (int r=0;r<8;++r) Ys[yl][r*17+j] = Yo[r];
    }
    __syncthreads();
    for (int o = threadIdx.x; o < YCH*NKZ; o += 256) {
        int kz = o / YCH, yl = o - (o/YCH)*YCH;
        const float2* Yp = &Ys[yl][(kz&7)*17];
        DFT15_BODY(Yp, kz, re, im)
        C1[(x*NKZ + kz)*120 + y0 + yl] = make_float2(re, im);
    }
}

// stage 2: cfft along y (radix-8). block = (4 consecutive x, kz). out C2[kz][ky][x].
__global__ void __launch_bounds__(256)
fft_y_kernel(const float2* __restrict__ C1,
             float2* __restrict__ C2) {
    int xc = blockIdx.x / NKZ;
    int kz = blockIdx.x - xc*NKZ;
    int x0 = xc * XCH;
    __shared__ float2 lin[XCH][121];
    __shared__ float2 Ys[XCH][YROW];
    for (int i = threadIdx.x; i < XCH*120; i += 256) {
        int xo = i / 120, y = i - (i/120)*120;
        lin[xo][y] = C1[((x0+xo)*NKZ + kz)*120 + y];
    }
    __syncthreads();
    for (int t = threadIdx.x; t < XCH*15; t += 256) {
        int xo = t / 15, j = t - (t/15)*15;
        float2 xin[8], Yo[8];
        #pragma unroll
        for (int m=0;m<8;++m) xin[m] = lin[xo][15*m+j];
        dft8(xin, Yo);
        #pragma unroll
        for (int r=0;r<8;++r) Ys[xo][r*17+j] = Yo[r];
    }
    __syncthreads();
    for (int o = threadIdx.x; o < XCH*120; o += 256) {
        int ky = o >> 2, xo = o & 3;
        const float2* Yp = &Ys[xo][(ky&7)*17];
        DFT15_BODY(Yp, ky, re, im)
        C2[(kz*120 + ky)*120 + x0 + xo] = make_float2(re, im);
    }
}

// stage 3: cfft along x (radix-8) + G-weighted energy (slotted atomic).
__global__ void __launch_bounds__(256)
fft_x_energy_kernel(const float2* __restrict__ C2,
                    const float* __restrict__ box,
                    double* __restrict__ ekslots) {
    int kyc = blockIdx.x / NKZ;
    int kz  = blockIdx.x - kyc*NKZ;
    int ky0 = kyc * XCH;
    __shared__ float2 lin[XCH][121];
    __shared__ float2 Ys[XCH][YROW];
    const float2* src = C2 + (kz*120 + ky0)*120;
    for (int i = threadIdx.x; i < XCH*120; i += 256) {
        int kyo = i / 120, xx = i - (i/120)*120;
        lin[kyo][xx] = src[i];
    }
    __syncthreads();
    for (int t = threadIdx.x; t < XCH*15; t += 256) {
        int kyo = t / 15, j = t - (t/15)*15;
        float2 xin[8], Yo[8];
        #pragma unroll
        for (int m=0;m<8;++m) xin[m] = lin[kyo][15*m+j];
        dft8(xin, Yo);
        #pragma unroll
        for (int r=0;r<8;++r) Ys[kyo][r*17+j] = Yo[r];
    }
    __syncthreads();
    float ib[9]; inv3(box, ib);
    const float TWOPI = 6.283185307179586f;
    float wzf = (kz==0 || kz==60) ? 1.0f : 2.0f;
    float contrib = 0.f;
    for (int o = threadIdx.x; o < XCH*120; o += 256) {
        int kyo = o / 120, kx = o - (o/120)*120;
        int ky = ky0 + kyo;
        const float2* Yp = &Ys[kyo][(kx&7)*17];
        DFT15_BODY(Yp, kx, re, im)
        if (!(kx==0 && ky==0 && kz==0)) {
            float mx = (kx < 60) ? (float)kx : (float)(kx - 120);
            float my = (ky < 60) ? (float)ky : (float)(ky - 120);
            float mz = (float)kz;
            float k0 = TWOPI*(mx*ib[0] + my*ib[1] + mz*ib[2]);
            float k1 = TWOPI*(mx*ib[3] + my*ib[4] + mz*ib[5]);
            float k2 = TWOPI*(mx*ib[6] + my*ib[7] + mz*ib[8]);
            float ksq = k0*k0 + k1*k1 + k2*k2;
            float G = 12.566370614359172f * __expf(-0.5f*(float)(ALPHA_C*ALPHA_C)*ksq) / ksq;
            contrib += wzf * G * (re*re + im*im);
        }
    }
    #pragma unroll
    for (int o=32;o>0;o>>=1) contrib += __shfl_down(contrib,o,64);
    __shared__ float sm[4];
    int lane = threadIdx.x & 63, w = threadIdx.x >> 6;
    if (lane==0) sm[w] = contrib;
    __syncthreads();
    if (threadIdx.x==0)
        atomicAdd(&ekslots[(blockIdx.x & (NSLOT-1)) * SLOTSTRIDE],
                  (double)(sm[0]+sm[1]+sm[2]+sm[3]));
}

// 64-lane slot reduction + closed-form corrections
__global__ void finalize_kernel(const double* __restrict__ ekslots,
                                const double* __restrict__ qslots,
                                const double* __restrict__ q2slots,
                                const float* __restrict__ box,
                                float* __restrict__ out) {
    int lane = threadIdx.x;
    double ek  = ekslots[lane*SLOTSTRIDE];
    double sq  = qslots [lane*SLOTSTRIDE];
    double sq2 = q2slots[lane*SLOTSTRIDE];
    #pragma unroll
    for (int o=32;o>0;o>>=1) {
        ek  += __shfl_down(ek,  o, 64);
        sq  += __shfl_down(sq,  o, 64);
        sq2 += __shfl_down(sq2, o, 64);
    }
    if (lane == 0) {
        double a00=box[0],a01=box[1],a02=box[2],a10=box[3],a11=box[4],a12=box[5],a20=box[6],a21=box[7],a22=box[8];
        double det = a00*(a11*a22-a12*a21) - a01*(a10*a22-a12*a20) + a02*(a10*a21-a11*a20);
        double vol = fabs(det);
        double E = ek/(2.0*vol)
                 - 0.5*sqrt(2.0/M_PI)/ALPHA_C * sq2
                 - M_PI*ALPHA_C*ALPHA_C * sq*sq / vol;
        out[0] = (float)E;
    }
}

extern "C" void kernel_launch(void* const* d_in, const int* in_sizes, int n_in,
                              void* d_out, int out_size, void* d_ws, size_t ws_size,
                              hipStream_t stream) {
    const float* coords  = (const float*)d_in[0];
    const float* box     = (const float*)d_in[1];
    const float* charges = (const float*)d_in[2];
    int n = in_sizes[0] / 3;

    char* ws = (char*)d_ws;
    double* ekslots = (double*)(ws + EK_OFF);
    double* qslots  = (double*)(ws + Q_OFF);
    double* q2slots = (double*)(ws + Q2_OFF);
    float*  buf     = (float*) (ws + BUF_OFF);
    float2* C1      = (float2*)(ws + C1_OFF);
    float2* C2      = (float2*)(ws + C2_OFF);
    int* counts     = (int*)(ws + COUNTS_OFF);
    float4* sorted  = (float4*)(ws + SORTED_OFF);

    int gA = (n + 255)/256;
    init_kernel<<<1, 1024, 0, stream>>>(counts, ekslots);
    scatter_q_kernel<<<gA, 256, 0, stream>>>(coords, box, charges, counts, sorted, qslots, q2slots, n);
    spread_tile_kernel<<<NTILE, 256, 0, stream>>>(sorted, counts, buf);
    fft_z_kernel<<<120*10, 256, 0, stream>>>(buf, C1);
    fft_y_kernel<<<30*NKZ, 256, 0, stream>>>(C1, C2);
    fft_x_energy_kernel<<<NKZ*30, 256, 0, stream>>>(C2, box, ekslots);
    finalize_kernel<<<1, 64, 0, stream>>>(ekslots, qslots, q2slots, box, (float*)d_out);
}

// Round 2
// 254.814 us; speedup vs baseline: 1.0043x; 1.0043x over previous
//
#include <hip/hip_runtime.h>
#include <math.h>

#define NMESH 120
#define NKZ 61            // rfft half-spectrum along z
#define NTOT (120*120*120)
#define ALPHA_C 1.0

#define TILE 12           // mesh cells per tile per dim
#define NTPD 10           // tiles per dim
#define NTILE 1000
#define FP 17             // footprint per dim: TILE + 5
#define FPCELLS (FP*FP*FP)   // 4913
#define FPSTRIDE 4928        // padded tile stride (buf layout)
#define SA 292               // LDS accS a-stride: banks (4a+17b)%32 -> max 2-way (free)
#define SACC 4961            // accS size (single shared copy, ds_add_f32 accumulation)
#define CAP 256              // bucket capacity (Poisson(100): overflow ~1e-40)

#define YCH 12            // y-lines per fft_z block (1200 blocks)
#define XCH 4             // x per fft_y block / ky per fft_x block
#define YROW 137          // per-line Y storage: 8 rows * 17 + 1 pad (float2)

#define NSLOT 64          // accumulator slots (64B apart)
#define SLOTSTRIDE 8      // doubles per slot

// ---- workspace layout (bytes) ----
// [0, 4096)      : double ekslots[64*8]
// [4096, 8192)   : double qslots [64*8]
// [8192, 12288)  : double q2slots[64*8]
// [115264, +19712000)  : float buf[1000][4928] tile footprints
// [19827264, +7027200) : float2 C1[x][kz][y]
//    counts + CAP-padded sorted atoms ALIAS the C1 region (dead before fft_z writes C1)
// C2[kz][ky][x] ALIASES buf (buf dead after fft_z)
#define EK_OFF      0
#define Q_OFF       4096
#define Q2_OFF      8192
#define BUF_OFF     115264
#define C1_OFF      19827264
#define C2_OFF      115264
#define COUNTS_OFF  C1_OFF
#define SORTED_OFF  (C1_OFF + 4096)

__device__ inline void inv3(const float* b, float* ib) {
    float a00=b[0],a01=b[1],a02=b[2],a10=b[3],a11=b[4],a12=b[5],a20=b[6],a21=b[7],a22=b[8];
    float c00 =  a11*a22 - a12*a21;
    float c01 = -(a10*a22 - a12*a20);
    float c02 =  a10*a21 - a11*a20;
    float c10 = -(a01*a22 - a02*a21);
    float c11 =  a00*a22 - a02*a20;
    float c12 = -(a00*a21 - a01*a20);
    float c20 =  a01*a12 - a02*a11;
    float c21 = -(a00*a12 - a02*a10);
    float c22 =  a00*a11 - a01*a10;
    float det = a00*c00 + a01*c01 + a02*c02;
    float inv = 1.0f/det;
    ib[0]=c00*inv; ib[1]=c10*inv; ib[2]=c20*inv;
    ib[3]=c01*inv; ib[4]=c11*inv; ib[5]=c21*inv;
    ib[6]=c02*inv; ib[7]=c12*inv; ib[8]=c22*inv;
}

__device__ inline void atom_pos(const float* __restrict__ box, float c0, float c1, float c2,
                                float* p) {
    float ib[9]; inv3(box, ib);
    #pragma unroll
    for (int d=0; d<3; ++d)
        p[d] = (c0*ib[0+d] + c1*ib[3+d] + c2*ib[6+d]) * 120.0f;
}

__device__ inline int wrap120(int i) { return ((i % 120) + 120) % 120; }

// order-6 Lagrange weights; x = pos - (floor(pos)+0.5)
__device__ inline void lag6(float x, float* w) {
    float df[6];
    #pragma unroll
    for (int k=0;k<6;++k) df[k] = x - ((float)k - 2.5f);
    w[0] = df[1]*df[2]*df[3]*df[4]*df[5] * (-1.0f/120.0f);
    w[1] = df[0]*df[2]*df[3]*df[4]*df[5] * ( 1.0f/24.0f);
    w[2] = df[0]*df[1]*df[3]*df[4]*df[5] * (-1.0f/12.0f);
    w[3] = df[0]*df[1]*df[2]*df[4]*df[5] * ( 1.0f/12.0f);
    w[4] = df[0]*df[1]*df[2]*df[3]*df[5] * (-1.0f/24.0f);
    w[5] = df[0]*df[1]*df[2]*df[3]*df[4] * ( 1.0f/120.0f);
}

// per-dim halo decomposition: cell c -> up to 2 (tile, local) pairs
__device__ inline int halo_pairs(int c, int* t, int* l) {
    int r = c % 12, ti = c / 12, n = 0;
    t[n] = ti;          l[n] = r + 2;  n++;
    if (r < 3)  { t[n] = (ti+9)%10; l[n] = r + 14; n++; }
    if (r >= 10){ t[n] = (ti+1)%10; l[n] = r - 10; n++; }
    return n;
}

// 8-point DFT, complex in (m-order), complex out (k-order). W8 = e^{-2pi i/8}.
__device__ inline void dft8(const float2* xin, float2* Y) {
    const float S = 0.70710678118654752f;
    float2 a=xin[0], b=xin[2], c=xin[4], d=xin[6];
    float s02r=a.x+c.x, s02i=a.y+c.y, d02r=a.x-c.x, d02i=a.y-c.y;
    float s13r=b.x+d.x, s13i=b.y+d.y, d13r=b.x-d.x, d13i=b.y-d.y;
    float2 E0 = make_float2(s02r+s13r, s02i+s13i);
    float2 E1 = make_float2(d02r+d13i, d02i-d13r);   // d02 - i*d13
    float2 E2 = make_float2(s02r-s13r, s02i-s13i);
    float2 E3 = make_float2(d02r-d13i, d02i+d13r);
    a=xin[1]; b=xin[3]; c=xin[5]; d=xin[7];
    s02r=a.x+c.x; s02i=a.y+c.y; d02r=a.x-c.x; d02i=a.y-c.y;
    s13r=b.x+d.x; s13i=b.y+d.y; d13r=b.x-d.x; d13i=b.y-d.y;
    float2 O0 = make_float2(s02r+s13r, s02i+s13i);
    float2 O1 = make_float2(d02r+d13i, d02i-d13r);
    float2 O2 = make_float2(s02r-s13r, s02i-s13i);
    float2 O3 = make_float2(d02r-d13i, d02i+d13r);
    float t1r = S*(O1.x + O1.y), t1i = S*(O1.y - O1.x);   // W8^1 * O1
    float t2r = O2.y,            t2i = -O2.x;             // W8^2 = -i
    float t3r = S*(O3.y - O3.x), t3i = -S*(O3.x + O3.y);  // W8^3
    Y[0] = make_float2(E0.x + O0.x, E0.y + O0.y);
    Y[4] = make_float2(E0.x - O0.x, E0.y - O0.y);
    Y[1] = make_float2(E1.x + t1r,  E1.y + t1i);
    Y[5] = make_float2(E1.x - t1r,  E1.y - t1i);
    Y[2] = make_float2(E2.x + t2r,  E2.y + t2i);
    Y[6] = make_float2(E2.x - t2r,  E2.y - t2i);
    Y[3] = make_float2(E3.x + t3r,  E3.y + t3i);
    Y[7] = make_float2(E3.x - t3r,  E3.y - t3i);
}

__global__ void init_kernel(int* __restrict__ counts, double* __restrict__ slots) {
    int idx = threadIdx.x;
    for (int i = idx; i < 3*NSLOT*SLOTSTRIDE; i += 1024) slots[i] = 0.0;
    for (int i = idx; i < NTILE; i += 1024) counts[i] = 0;
}

// one-pass bucket scatter + sum(q) + sum(q^2) into per-slot accumulators
__global__ void scatter_q_kernel(const float* __restrict__ coords,
                                 const float* __restrict__ box,
                                 const float* __restrict__ charges,
                                 int* __restrict__ counts,
                                 float4* __restrict__ sorted,
                                 double* __restrict__ qslots,
                                 double* __restrict__ q2slots, int n) {
    int i = blockIdx.x*blockDim.x + threadIdx.x;
    float v = 0.f, v2 = 0.f;
    if (i < n) {
        float p[3]; atom_pos(box, coords[3*i], coords[3*i+1], coords[3*i+2], p);
        float q = charges[i];
        v = q; v2 = q*q;
        int t[3];
        #pragma unroll
        for (int d=0; d<3; ++d) t[d] = wrap120((int)floorf(p[d])) / TILE;
        int tile = (t[0]*NTPD + t[1])*NTPD + t[2];
        int idx = atomicAdd(&counts[tile], 1);
        if (idx < CAP) sorted[tile*CAP + idx] = make_float4(p[0], p[1], p[2], q);
    }
    #pragma unroll
    for (int o=32;o>0;o>>=1) { v += __shfl_down(v,o,64); v2 += __shfl_down(v2,o,64); }
    __shared__ float s1[4], s2[4];
    int lane = threadIdx.x & 63, w = threadIdx.x >> 6;
    if (lane==0) { s1[w]=v; s2[w]=v2; }
    __syncthreads();
    if (threadIdx.x==0) {
        for (int j=1;j<4;j++) { v += s1[j]; v2 += s2[j]; }
        int slot = (blockIdx.x & (NSLOT-1)) * SLOTSTRIDE;
        atomicAdd(&qslots[slot],  (double)v);
        atomicAdd(&q2slots[slot], (double)v2);
    }
}

// FOUR waves per tile; single shared accS; HW ds_add_f32 via inline asm.
// Round-1 post-mortem: HIP atomicAdd(float) on LDS expanded to a CAS/flat
// retry loop (131 us, VALUBusy 3%). Same verified item-flattened structure,
// but the f32 LDS add is now emitted directly: fire-and-forget ds_add_f32,
// one address VGPR + offset:{0..20} immediates for the 6 z-taps.
// LDS byte address = low 32 bits of generic pointer (shared aperture is
// 4 GiB-aligned on CDNA). Inline-asm DS ops are invisible to the compiler's
// waitcnt tracking -> explicit s_waitcnt lgkmcnt(0) before each barrier.
__global__ void __launch_bounds__(256)
spread_tile_kernel(const float4* __restrict__ sorted,
                   const int* __restrict__ counts,
                   float* __restrict__ buf) {
    int tile = blockIdx.x;
    int tx = tile / (NTPD*NTPD);
    int rem = tile - tx*NTPD*NTPD;
    int ty = rem / NTPD;
    int tz = rem - ty*NTPD;
    int bx = tx*TILE, by = ty*TILE, bz = tz*TILE;

    __shared__ float accS[SACC];
    __shared__ float W[256][18];
    __shared__ int   baseS[256];

    int tid = threadIdx.x;
    for (int i = tid; i < SACC; i += 256) accS[i] = 0.f;

    uint32_t accBase = (uint32_t)(uintptr_t)&accS[0];

    int cntT = min(counts[tile], CAP);
    const float4* src = sorted + tile*CAP;

    for (int start = 0; start < cntT; start += 256) {
        int my = start + tid;
        if (my < cntT) {
            float4 s = src[my];
            float fx = floorf(s.x);
            float wx[6]; lag6(s.x - (fx + 0.5f), wx);
            float fy = floorf(s.y);
            float wy[6]; lag6(s.y - (fy + 0.5f), wy);
            float fz = floorf(s.z);
            float wz[6]; lag6(s.z - (fz + 0.5f), wz);
            int lx = wrap120((int)fx) - bx;
            int ly = wrap120((int)fy) - by;
            int lz = wrap120((int)fz) - bz;
            baseS[tid] = lx*SA + ly*FP + lz;
            #pragma unroll
            for (int k=0;k<6;++k) {
                W[tid][k]    = wx[k]*s.w;
                W[tid][6+k]  = wy[k];
                W[tid][12+k] = wz[k];
            }
        }
        __syncthreads();
        int jn = cntT - start;
        jn = (jn > 256) ? 256 : jn;
        int nitems = jn * 36;
        for (int it = tid; it < nitems; it += 256) {
            int row = it / 36;
            int ab  = it - row*36;
            int a   = ab / 6;
            int b   = ab - a*6;
            float w2 = W[row][a] * W[row][6+b];
            float2 wz01 = *(const float2*)&W[row][12];
            float2 wz23 = *(const float2*)&W[row][14];
            float2 wz45 = *(const float2*)&W[row][16];
            uint32_t ad = accBase + 4u*(uint32_t)(baseS[row] + a*SA + b*FP);
            float v0 = w2*wz01.x, v1 = w2*wz01.y;
            float v2 = w2*wz23.x, v3 = w2*wz23.y;
            float v4 = w2*wz45.x, v5 = w2*wz45.y;
            asm volatile("ds_add_f32 %0, %1 offset:0"  :: "v"(ad), "v"(v0) : "memory");
            asm volatile("ds_add_f32 %0, %1 offset:4"  :: "v"(ad), "v"(v1) : "memory");
            asm volatile("ds_add_f32 %0, %1 offset:8"  :: "v"(ad), "v"(v2) : "memory");
            asm volatile("ds_add_f32 %0, %1 offset:12" :: "v"(ad), "v"(v3) : "memory");
            asm volatile("ds_add_f32 %0, %1 offset:16" :: "v"(ad), "v"(v4) : "memory");
            asm volatile("ds_add_f32 %0, %1 offset:20" :: "v"(ad), "v"(v5) : "memory");
        }
        asm volatile("s_waitcnt lgkmcnt(0)" ::: "memory");
        __syncthreads();
    }

    for (int i = tid; i < FPCELLS; i += 256) {
        int lx = i / (FP*FP);
        int r  = i - lx*FP*FP;
        int ly = r / FP;
        int lz = r - ly*FP;
        int ai = lx*SA + ly*FP + lz;
        buf[(size_t)tile * FPSTRIDE + i] = accS[ai];
    }
}

// ---- radix-8 decimated 120-point DFT inner loop ----
// X[k] = sum_{j<15} Y[k&7][j] * W120^{k*j};  3 strands (j mod 3) for ILP.
#define DFT15_BODY(Yp, kfreq, RE, IM)                                        \
    float w1r, w1i;                                                          \
    __sincosf(-0.052359877559829887f * (float)(kfreq), &w1i, &w1r);          \
    float w2r = w1r*w1r - w1i*w1i, w2i = 2.f*w1r*w1i;                        \
    float w3r = w2r*w1r - w2i*w1i, w3i = w2r*w1i + w2i*w1r;                  \
    float ar=1.f, ai=0.f, br=w1r, bi=w1i, cr=w2r, ci=w2i;                    \
    float r0_=0.f,i0_=0.f,r1_=0.f,i1_=0.f,r2_=0.f,i2_=0.f;                   \
    _Pragma("unroll")                                                        \
    for (int s_=0;s_<5;++s_) {                                               \
        float2 ya = (Yp)[3*s_], yb = (Yp)[3*s_+1], yc = (Yp)[3*s_+2];        \
        r0_ = fmaf(ya.x, ar, fmaf(-ya.y, ai, r0_));                          \
        i0_ = fmaf(ya.x, ai, fmaf( ya.y, ar, i0_));                          \
        r1_ = fmaf(yb.x, br, fmaf(-yb.y, bi, r1_));                          \
        i1_ = fmaf(yb.x, bi, fmaf( yb.y, br, i1_));                          \
        r2_ = fmaf(yc.x, cr, fmaf(-yc.y, ci, r2_));                          \
        i2_ = fmaf(yc.x, ci, fmaf( yc.y, cr, i2_));                          \
        float n_;                                                            \
        n_ = ar*w3r - ai*w3i; ai = ar*w3i + ai*w3r; ar = n_;                 \
        n_ = br*w3r - bi*w3i; bi = br*w3i + bi*w3r; br = n_;                 \
        n_ = cr*w3r - ci*w3i; ci = cr*w3i + ci*w3r; cr = n_;                 \
    }                                                                        \
    float RE = (r0_+r1_)+r2_, IM = (i0_+i1_)+i2_;

// stage 1: halo-gather + rfft along z (radix-8 pre-combine). out C1[x][kz][y].
__global__ void __launch_bounds__(256)
fft_z_kernel(const float* __restrict__ buf,
             float2* __restrict__ C1) {
    int x  = blockIdx.x / 10;
    int y0 = (blockIdx.x - x*10) * YCH;
    __shared__ float  lin[YCH][121];
    __shared__ float2 Ys[YCH][YROW];    // per line: 8 rows * 17 (+1 pad)

    int txA[2], lxA[2];
    int nx = halo_pairs(x, txA, lxA);

    for (int i = threadIdx.x; i < YCH*120; i += 256) {
        int yl = i / 120, z = i - yl*120;
        int tyA[2], lyA[2]; int ny = halo_pairs(y0 + yl, tyA, lyA);
        int tzA[2], lzA[2]; int nz = halo_pairs(z, tzA, lzA);
        float s = 0.f;
        for (int ii=0; ii<nx; ++ii)
            for (int jj=0; jj<ny; ++jj)
                for (int kk=0; kk<nz; ++kk) {
                    int tile = (txA[ii]*NTPD + tyA[jj])*NTPD + tzA[kk];
                    int cell = (lxA[ii]*FP + lyA[jj])*FP + lzA[kk];
                    s += buf[(size_t)tile*FPSTRIDE + cell];
                }
        lin[yl][z] = s;
    }
    __syncthreads();
    // radix-8 combine: z = 15m + j ; Y[r][j] = sum_m x W8^{rm}
    for (int t = threadIdx.x; t < YCH*15; t += 256) {
        int yl = t / 15, j = t - (t/15)*15;
        float2 xin[8], Yo[8];
        #pragma unroll
        for (int m=0;m<8;++m) xin[m] = make_float2(lin[yl][15*m+j], 0.f);
        dft8(xin, Yo);
        #pragma unroll
        for (int r=0;r<8;++r) Ys[yl][r*17+j] = Yo[r];
    }
    __syncthreads();
    for (int o = threadIdx.x; o < YCH*NKZ; o += 256) {
        int kz = o / YCH, yl = o - (o/YCH)*YCH;
        const float2* Yp = &Ys[yl][(kz&7)*17];
        DFT15_BODY(Yp, kz, re, im)
        C1[(x*NKZ + kz)*120 + y0 + yl] = make_float2(re, im);
    }
}

// stage 2: cfft along y (radix-8). block = (4 consecutive x, kz). out C2[kz][ky][x].
__global__ void __launch_bounds__(256)
fft_y_kernel(const float2* __restrict__ C1,
             float2* __restrict__ C2) {
    int xc = blockIdx.x / NKZ;
    int kz = blockIdx.x - xc*NKZ;
    int x0 = xc * XCH;
    __shared__ float2 lin[XCH][121];
    __shared__ float2 Ys[XCH][YROW];
    for (int i = threadIdx.x; i < XCH*120; i += 256) {
        int xo = i / 120, y = i - (i/120)*120;
        lin[xo][y] = C1[((x0+xo)*NKZ + kz)*120 + y];
    }
    __syncthreads();
    for (int t = threadIdx.x; t < XCH*15; t += 256) {
        int xo = t / 15, j = t - (t/15)*15;
        float2 xin[8], Yo[8];
        #pragma unroll
        for (int m=0;m<8;++m) xin[m] = lin[xo][15*m+j];
        dft8(xin, Yo);
        #pragma unroll
        for (int r=0;r<8;++r) Ys[xo][r*17+j] = Yo[r];
    }
    __syncthreads();
    for (int o = threadIdx.x; o < XCH*120; o += 256) {
        int ky = o >> 2, xo = o & 3;
        const float2* Yp = &Ys[xo][(ky&7)*17];
        DFT15_BODY(Yp, ky, re, im)
        C2[(kz*120 + ky)*120 + x0 + xo] = make_float2(re, im);
    }
}

// stage 3: cfft along x (radix-8) + G-weighted energy (slotted atomic).
__global__ void __launch_bounds__(256)
fft_x_energy_kernel(const float2* __restrict__ C2,
                    const float* __restrict__ box,
                    double* __restrict__ ekslots) {
    int kyc = blockIdx.x / NKZ;
    int kz  = blockIdx.x - kyc*NKZ;
    int ky0 = kyc * XCH;
    __shared__ float2 lin[XCH][121];
    __shared__ float2 Ys[XCH][YROW];
    const float2* src = C2 + (kz*120 + ky0)*120;
    for (int i = threadIdx.x; i < XCH*120; i += 256) {
        int kyo = i / 120, xx = i - (i/120)*120;
        lin[kyo][xx] = src[i];
    }
    __syncthreads();
    for (int t = threadIdx.x; t < XCH*15; t += 256) {
        int kyo = t / 15, j = t - (t/15)*15;
        float2 xin[8], Yo[8];
        #pragma unroll
        for (int m=0;m<8;++m) xin[m] = lin[kyo][15*m+j];
        dft8(xin, Yo);
        #pragma unroll
        for (int r=0;r<8;++r) Ys[kyo][r*17+j] = Yo[r];
    }
    __syncthreads();
    float ib[9]; inv3(box, ib);
    const float TWOPI = 6.283185307179586f;
    float wzf = (kz==0 || kz==60) ? 1.0f : 2.0f;
    float contrib = 0.f;
    for (int o = threadIdx.x; o < XCH*120; o += 256) {
        int kyo = o / 120, kx = o - (o/120)*120;
        int ky = ky0 + kyo;
        const float2* Yp = &Ys[kyo][(kx&7)*17];
        DFT15_BODY(Yp, kx, re, im)
        if (!(kx==0 && ky==0 && kz==0)) {
            float mx = (kx < 60) ? (float)kx : (float)(kx - 120);
            float my = (ky < 60) ? (float)ky : (float)(ky - 120);
            float mz = (float)kz;
            float k0 = TWOPI*(mx*ib[0] + my*ib[1] + mz*ib[2]);
            float k1 = TWOPI*(mx*ib[3] + my*ib[4] + mz*ib[5]);
            float k2 = TWOPI*(mx*ib[6] + my*ib[7] + mz*ib[8]);
            float ksq = k0*k0 + k1*k1 + k2*k2;
            float G = 12.566370614359172f * __expf(-0.5f*(float)(ALPHA_C*ALPHA_C)*ksq) / ksq;
            contrib += wzf * G * (re*re + im*im);
        }
    }
    #pragma unroll
    for (int o=32;o>0;o>>=1) contrib += __shfl_down(contrib,o,64);
    __shared__ float sm[4];
    int lane = threadIdx.x & 63, w = threadIdx.x >> 6;
    if (lane==0) sm[w] = contrib;
    __syncthreads();
    if (threadIdx.x==0)
        atomicAdd(&ekslots[(blockIdx.x & (NSLOT-1)) * SLOTSTRIDE],
                  (double)(sm[0]+sm[1]+sm[2]+sm[3]));
}

// 64-lane slot reduction + closed-form corrections
__global__ void finalize_kernel(const double* __restrict__ ekslots,
                                const double* __restrict__ qslots,
                                const double* __restrict__ q2slots,
                                const float* __restrict__ box,
                                float* __restrict__ out) {
    int lane = threadIdx.x;
    double ek  = ekslots[lane*SLOTSTRIDE];
    double sq  = qslots [lane*SLOTSTRIDE];
    double sq2 = q2slots[lane*SLOTSTRIDE];
    #pragma unroll
    for (int o=32;o>0;o>>=1) {
        ek  += __shfl_down(ek,  o, 64);
        sq  += __shfl_down(sq,  o, 64);
        sq2 += __shfl_down(sq2, o, 64);
    }
    if (lane == 0) {
        double a00=box[0],a01=box[1],a02=box[2],a10=box[3],a11=box[4],a12=box[5],a20=box[6],a21=box[7],a22=box[8];
        double det = a00*(a11*a22-a12*a21) - a01*(a10*a22-a12*a20) + a02*(a10*a21-a11*a20);
        double vol = fabs(det);
        double E = ek/(2.0*vol)
                 - 0.5*sqrt(2.0/M_PI)/ALPHA_C * sq2
                 - M_PI*ALPHA_C*ALPHA_C * sq*sq / vol;
        out[0] = (float)E;
    }
}

extern "C" void kernel_launch(void* const* d_in, const int* in_sizes, int n_in,
                              void* d_out, int out_size, void* d_ws, size_t ws_size,
                              hipStream_t stream) {
    const float* coords  = (const float*)d_in[0];
    const float* box     = (const float*)d_in[1];
    const float* charges = (const float*)d_in[2];
    int n = in_sizes[0] / 3;

    char* ws = (char*)d_ws;
    double* ekslots = (double*)(ws + EK_OFF);
    double* qslots  = (double*)(ws + Q_OFF);
    double* q2slots = (double*)(ws + Q2_OFF);
    float*  buf     = (float*) (ws + BUF_OFF);
    float2* C1      = (float2*)(ws + C1_OFF);
    float2* C2      = (float2*)(ws + C2_OFF);
    int* counts     = (int*)(ws + COUNTS_OFF);
    float4* sorted  = (float4*)(ws + SORTED_OFF);

    int gA = (n + 255)/256;
    init_kernel<<<1, 1024, 0, stream>>>(counts, ekslots);
    scatter_q_kernel<<<gA, 256, 0, stream>>>(coords, box, charges, counts, sorted, qslots, q2slots, n);
    spread_tile_kernel<<<NTILE, 256, 0, stream>>>(sorted, counts, buf);
    fft_z_kernel<<<120*10, 256, 0, stream>>>(buf, C1);
    fft_y_kernel<<<30*NKZ, 256, 0, stream>>>(C1, C2);
    fft_x_energy_kernel<<<NKZ*30, 256, 0, stream>>>(C2, box, ekslots);
    finalize_kernel<<<1, 64, 0, stream>>>(ekslots, qslots, q2slots, box, (float*)d_out);
}

// Round 3
// 155.358 us; speedup vs baseline: 1.6473x; 1.6402x over previous
//
#include <hip/hip_runtime.h>
#include <math.h>

#define NMESH 120
#define NKZ 61            // rfft half-spectrum along z
#define NTOT (120*120*120)
#define ALPHA_C 1.0

#define TILE 12           // mesh cells per tile per dim
#define NTPD 10           // tiles per dim
#define NTILE 1000
#define FP 17             // footprint per dim: TILE + 5
#define FPCELLS (FP*FP*FP)   // 4913
#define FPSTRIDE 4928        // padded tile stride (buf layout)
#define CAP 256              // bucket capacity (Poisson(100): overflow ~1e-40)

#define CHUNK 128            // atoms staged per pass (P(cnt>128) ~ 0.3%)
// spread smem layout (floats)
#define WXA_OFF 0                    // [CHUNK][17] zero-padded |wx*1|
#define WYA_OFF (CHUNK*17)           // [CHUNK][17]
#define WZA_OFF (2*CHUNK*17)         // [CHUNK][20] stride 20 -> 16B aligned rows
#define LXS_OFF (2*CHUNK*17 + CHUNK*20)  // int[CHUNK]
#define SMEMF   (LXS_OFF + CHUNK)    // 7040 floats = 28160 B

#define YCH 12            // y-lines per fft_z block (1200 blocks)
#define XCH 4             // x per fft_y block / ky per fft_x block
#define YROW 137          // per-line Y storage: 8 rows * 17 + 1 pad (float2)

#define NSLOT 64          // accumulator slots (64B apart)
#define SLOTSTRIDE 8      // doubles per slot

// ---- workspace layout (bytes) ----
// [0, 4096)      : double ekslots[64*8]
// [4096, 8192)   : double qslots [64*8]
// [8192, 12288)  : double q2slots[64*8]
// [115264, +19712000)  : float buf[1000][4928] tile footprints
// [19827264, +7027200) : float2 C1[x][kz][y]
//    counts + CAP-padded sorted atoms ALIAS the C1 region (dead before fft_z writes C1)
// C2[kz][ky][x] ALIASES buf (buf dead after fft_z)
#define EK_OFF      0
#define Q_OFF       4096
#define Q2_OFF      8192
#define BUF_OFF     115264
#define C1_OFF      19827264
#define C2_OFF      115264
#define COUNTS_OFF  C1_OFF
#define SORTED_OFF  (C1_OFF + 4096)

__device__ inline void inv3(const float* b, float* ib) {
    float a00=b[0],a01=b[1],a02=b[2],a10=b[3],a11=b[4],a12=b[5],a20=b[6],a21=b[7],a22=b[8];
    float c00 =  a11*a22 - a12*a21;
    float c01 = -(a10*a22 - a12*a20);
    float c02 =  a10*a21 - a11*a20;
    float c10 = -(a01*a22 - a02*a21);
    float c11 =  a00*a22 - a02*a20;
    float c12 = -(a00*a21 - a01*a20);
    float c20 =  a01*a12 - a02*a11;
    float c21 = -(a00*a12 - a02*a10);
    float c22 =  a00*a11 - a01*a10;
    float det = a00*c00 + a01*c01 + a02*c02;
    float inv = 1.0f/det;
    ib[0]=c00*inv; ib[1]=c10*inv; ib[2]=c20*inv;
    ib[3]=c01*inv; ib[4]=c11*inv; ib[5]=c21*inv;
    ib[6]=c02*inv; ib[7]=c12*inv; ib[8]=c22*inv;
}

__device__ inline void atom_pos(const float* __restrict__ box, float c0, float c1, float c2,
                                float* p) {
    float ib[9]; inv3(box, ib);
    #pragma unroll
    for (int d=0; d<3; ++d)
        p[d] = (c0*ib[0+d] + c1*ib[3+d] + c2*ib[6+d]) * 120.0f;
}

__device__ inline int wrap120(int i) { return ((i % 120) + 120) % 120; }

// order-6 Lagrange weights; x = pos - (floor(pos)+0.5)
__device__ inline void lag6(float x, float* w) {
    float df[6];
    #pragma unroll
    for (int k=0;k<6;++k) df[k] = x - ((float)k - 2.5f);
    w[0] = df[1]*df[2]*df[3]*df[4]*df[5] * (-1.0f/120.0f);
    w[1] = df[0]*df[2]*df[3]*df[4]*df[5] * ( 1.0f/24.0f);
    w[2] = df[0]*df[1]*df[3]*df[4]*df[5] * (-1.0f/12.0f);
    w[3] = df[0]*df[1]*df[2]*df[4]*df[5] * ( 1.0f/12.0f);
    w[4] = df[0]*df[1]*df[2]*df[3]*df[5] * (-1.0f/24.0f);
    w[5] = df[0]*df[1]*df[2]*df[3]*df[4] * ( 1.0f/120.0f);
}

// per-dim halo decomposition: cell c -> up to 2 (tile, local) pairs
__device__ inline int halo_pairs(int c, int* t, int* l) {
    int r = c % 12, ti = c / 12, n = 0;
    t[n] = ti;          l[n] = r + 2;  n++;
    if (r < 3)  { t[n] = (ti+9)%10; l[n] = r + 14; n++; }
    if (r >= 10){ t[n] = (ti+1)%10; l[n] = r - 10; n++; }
    return n;
}

// 8-point DFT, complex in (m-order), complex out (k-order). W8 = e^{-2pi i/8}.
__device__ inline void dft8(const float2* xin, float2* Y) {
    const float S = 0.70710678118654752f;
    float2 a=xin[0], b=xin[2], c=xin[4], d=xin[6];
    float s02r=a.x+c.x, s02i=a.y+c.y, d02r=a.x-c.x, d02i=a.y-c.y;
    float s13r=b.x+d.x, s13i=b.y+d.y, d13r=b.x-d.x, d13i=b.y-d.y;
    float2 E0 = make_float2(s02r+s13r, s02i+s13i);
    float2 E1 = make_float2(d02r+d13i, d02i-d13r);   // d02 - i*d13
    float2 E2 = make_float2(s02r-s13r, s02i-s13i);
    float2 E3 = make_float2(d02r-d13i, d02i+d13r);
    a=xin[1]; b=xin[3]; c=xin[5]; d=xin[7];
    s02r=a.x+c.x; s02i=a.y+c.y; d02r=a.x-c.x; d02i=a.y-c.y;
    s13r=b.x+d.x; s13i=b.y+d.y; d13r=b.x-d.x; d13i=b.y-d.y;
    float2 O0 = make_float2(s02r+s13r, s02i+s13i);
    float2 O1 = make_float2(d02r+d13i, d02i-d13r);
    float2 O2 = make_float2(s02r-s13r, s02i-s13i);
    float2 O3 = make_float2(d02r-d13i, d02i+d13r);
    float t1r = S*(O1.x + O1.y), t1i = S*(O1.y - O1.x);   // W8^1 * O1
    float t2r = O2.y,            t2i = -O2.x;             // W8^2 = -i
    float t3r = S*(O3.y - O3.x), t3i = -S*(O3.x + O3.y);  // W8^3
    Y[0] = make_float2(E0.x + O0.x, E0.y + O0.y);
    Y[4] = make_float2(E0.x - O0.x, E0.y - O0.y);
    Y[1] = make_float2(E1.x + t1r,  E1.y + t1i);
    Y[5] = make_float2(E1.x - t1r,  E1.y - t1i);
    Y[2] = make_float2(E2.x + t2r,  E2.y + t2i);
    Y[6] = make_float2(E2.x - t2r,  E2.y - t2i);
    Y[3] = make_float2(E3.x + t3r,  E3.y + t3i);
    Y[7] = make_float2(E3.x - t3r,  E3.y - t3i);
}

__global__ void init_kernel(int* __restrict__ counts, double* __restrict__ slots) {
    int idx = threadIdx.x;
    for (int i = idx; i < 3*NSLOT*SLOTSTRIDE; i += 1024) slots[i] = 0.0;
    for (int i = idx; i < NTILE; i += 1024) counts[i] = 0;
}

// one-pass bucket scatter + sum(q) + sum(q^2) into per-slot accumulators
__global__ void scatter_q_kernel(const float* __restrict__ coords,
                                 const float* __restrict__ box,
                                 const float* __restrict__ charges,
                                 int* __restrict__ counts,
                                 float4* __restrict__ sorted,
                                 double* __restrict__ qslots,
                                 double* __restrict__ q2slots, int n) {
    int i = blockIdx.x*blockDim.x + threadIdx.x;
    float v = 0.f, v2 = 0.f;
    if (i < n) {
        float p[3]; atom_pos(box, coords[3*i], coords[3*i+1], coords[3*i+2], p);
        float q = charges[i];
        v = q; v2 = q*q;
        int t[3];
        #pragma unroll
        for (int d=0; d<3; ++d) t[d] = wrap120((int)floorf(p[d])) / TILE;
        int tile = (t[0]*NTPD + t[1])*NTPD + t[2];
        int idx = atomicAdd(&counts[tile], 1);
        if (idx < CAP) sorted[tile*CAP + idx] = make_float4(p[0], p[1], p[2], q);
    }
    #pragma unroll
    for (int o=32;o>0;o>>=1) { v += __shfl_down(v,o,64); v2 += __shfl_down(v2,o,64); }
    __shared__ float s1[4], s2[4];
    int lane = threadIdx.x & 63, w = threadIdx.x >> 6;
    if (lane==0) { s1[w]=v; s2[w]=v2; }
    __syncthreads();
    if (threadIdx.x==0) {
        for (int j=1;j<4;j++) { v += s1[j]; v2 += s2[j]; }
        int slot = (blockIdx.x & (NSLOT-1)) * SLOTSTRIDE;
        atomicAdd(&qslots[slot],  (double)v);
        atomicAdd(&q2slots[slot], (double)v2);
    }
}

// Round-2 post-mortem: ds_add_f32 (round 2) == HIP atomicAdd (round 1) ==
// 132 us -> LDS f32 atomic RMW throughput (~0.3 lane-ops/cy/CU) is the wall,
// not instruction selection. This version has ZERO LDS accumulation:
// each thread owns one absolute (A,B) z-column of the 17^3 footprint and
// accumulates 17 cells in REGISTERS. Per atom: staging writes zero-padded
// absolute-indexed weight rows (wxa/wya/wza, q folded into wza); owners do
// 2 multicast gathers + 5 broadcast reads + 17 reg-FMAs. Out-of-patch
// threads multiply by stored 0 (uniform flow, no divergence, no RMW chain).
// Wave-uniform lx-span test (readlane-cached, no LDS) skips ~half the waves.
// 289 owners -> 320 threads, 5 waves, 28.2 KB LDS -> 5 blocks/CU.
__global__ void __launch_bounds__(320)
spread_tile_kernel(const float4* __restrict__ sorted,
                   const int* __restrict__ counts,
                   float* __restrict__ buf) {
    int tile = blockIdx.x;
    int tx = tile / (NTPD*NTPD);
    int rem = tile - tx*NTPD*NTPD;
    int ty = rem / NTPD;
    int tz = rem - ty*NTPD;
    int bx = tx*TILE, by = ty*TILE, bz = tz*TILE;

    __shared__ float smem[SMEMF];
    int* lxs = (int*)&smem[LXS_OFF];

    int tid = threadIdx.x;
    int A = tid / 17, B = tid - A*17;          // A<=18 for tail lanes (masked)
    float mask = (tid < 289) ? 1.f : 0.f;
    int wv = tid >> 6;
    int lane = tid & 63;
    int Alo = (wv*64)/17;
    int Ahi = (wv*64+63)/17; if (Ahi > 16) Ahi = 16;

    float acc[17];
    #pragma unroll
    for (int k=0;k<17;++k) acc[k] = 0.f;

    int cntT = min(counts[tile], CAP);
    const float4* src = sorted + tile*CAP;

    for (int start = 0; start < cntT; start += CHUNK) {
        int jn = cntT - start; if (jn > CHUNK) jn = CHUNK;
        __syncthreads();                        // prev-chunk readers done
        if (tid < jn) {
            float4 s = src[start + tid];
            float fx = floorf(s.x), fy = floorf(s.y), fz = floorf(s.z);
            float wx[6]; lag6(s.x - (fx + 0.5f), wx);
            float wy[6]; lag6(s.y - (fy + 0.5f), wy);
            float wz[6]; lag6(s.z - (fz + 0.5f), wz);
            int lx = wrap120((int)fx) - bx;
            int ly = wrap120((int)fy) - by;
            int lz = wrap120((int)fz) - bz;
            #pragma unroll
            for (int k=0;k<17;++k) { smem[WXA_OFF + tid*17 + k] = 0.f;
                                     smem[WYA_OFF + tid*17 + k] = 0.f; }
            #pragma unroll
            for (int k=0;k<20;++k)   smem[WZA_OFF + tid*20 + k] = 0.f;
            #pragma unroll
            for (int k=0;k<6;++k) {
                smem[WXA_OFF + tid*17 + lx + k] = wx[k];
                smem[WYA_OFF + tid*17 + ly + k] = wy[k];
                smem[WZA_OFF + tid*20 + lz + k] = wz[k]*s.w;
            }
            lxs[tid] = lx;
        }
        __syncthreads();
        // per-wave register cache of lx for readlane (no LDS in the skip test)
        int lxv0 = lxs[lane];
        int lxv1 = lxs[64 + lane];
        for (int j = 0; j < jn; ++j) {
            int lxj = __builtin_amdgcn_readlane(j < 64 ? lxv0 : lxv1, j & 63);
            if (lxj > Ahi || lxj + 5 < Alo) continue;   // wave-uniform skip
            float wx_ = smem[WXA_OFF + j*17 + A];
            float wy_ = smem[WYA_OFF + j*17 + B];
            float w2 = wx_ * wy_ * mask;
            const float4* zp = (const float4*)&smem[WZA_OFF + j*20];
            float4 z0 = zp[0], z1 = zp[1], z2 = zp[2], z3 = zp[3];
            float z16 = smem[WZA_OFF + j*20 + 16];
            float zv[17];
            zv[0]=z0.x;  zv[1]=z0.y;  zv[2]=z0.z;  zv[3]=z0.w;
            zv[4]=z1.x;  zv[5]=z1.y;  zv[6]=z1.z;  zv[7]=z1.w;
            zv[8]=z2.x;  zv[9]=z2.y;  zv[10]=z2.z; zv[11]=z2.w;
            zv[12]=z3.x; zv[13]=z3.y; zv[14]=z3.z; zv[15]=z3.w;
            zv[16]=z16;
            #pragma unroll
            for (int k=0;k<17;++k) acc[k] = fmaf(w2, zv[k], acc[k]);
        }
    }
    __syncthreads();
    // overlay: registers -> flat LDS footprint (index (A*17+B)*17+k == tid*17+k)
    if (tid < 289) {
        #pragma unroll
        for (int k=0;k<17;++k) smem[tid*17 + k] = acc[k];
    }
    __syncthreads();
    for (int i = tid; i < FPCELLS; i += 320)
        buf[(size_t)tile * FPSTRIDE + i] = smem[i];
}

// ---- radix-8 decimated 120-point DFT inner loop ----
// X[k] = sum_{j<15} Y[k&7][j] * W120^{k*j};  3 strands (j mod 3) for ILP.
#define DFT15_BODY(Yp, kfreq, RE, IM)                                        \
    float w1r, w1i;                                                          \
    __sincosf(-0.052359877559829887f * (float)(kfreq), &w1i, &w1r);          \
    float w2r = w1r*w1r - w1i*w1i, w2i = 2.f*w1r*w1i;                        \
    float w3r = w2r*w1r - w2i*w1i, w3i = w2r*w1i + w2i*w1r;                  \
    float ar=1.f, ai=0.f, br=w1r, bi=w1i, cr=w2r, ci=w2i;                    \
    float r0_=0.f,i0_=0.f,r1_=0.f,i1_=0.f,r2_=0.f,i2_=0.f;                   \
    _Pragma("unroll")                                                        \
    for (int s_=0;s_<5;++s_) {                                               \
        float2 ya = (Yp)[3*s_], yb = (Yp)[3*s_+1], yc = (Yp)[3*s_+2];        \
        r0_ = fmaf(ya.x, ar, fmaf(-ya.y, ai, r0_));                          \
        i0_ = fmaf(ya.x, ai, fmaf( ya.y, ar, i0_));                          \
        r1_ = fmaf(yb.x, br, fmaf(-yb.y, bi, r1_));                          \
        i1_ = fmaf(yb.x, bi, fmaf( yb.y, br, i1_));                          \
        r2_ = fmaf(yc.x, cr, fmaf(-yc.y, ci, r2_));                          \
        i2_ = fmaf(yc.x, ci, fmaf( yc.y, cr, i2_));                          \
        float n_;                                                            \
        n_ = ar*w3r - ai*w3i; ai = ar*w3i + ai*w3r; ar = n_;                 \
        n_ = br*w3r - bi*w3i; bi = br*w3i + bi*w3r; br = n_;                 \
        n_ = cr*w3r - ci*w3i; ci = cr*w3i + ci*w3r; cr = n_;                 \
    }                                                                        \
    float RE = (r0_+r1_)+r2_, IM = (i0_+i1_)+i2_;

// stage 1: halo-gather + rfft along z (radix-8 pre-combine). out C1[x][kz][y].
__global__ void __launch_bounds__(256)
fft_z_kernel(const float* __restrict__ buf,
             float2* __restrict__ C1) {
    int x  = blockIdx.x / 10;
    int y0 = (blockIdx.x - x*10) * YCH;
    __shared__ float  lin[YCH][121];
    __shared__ float2 Ys[YCH][YROW];    // per line: 8 rows * 17 (+1 pad)

    int txA[2], lxA[2];
    int nx = halo_pairs(x, txA, lxA);

    for (int i = threadIdx.x; i < YCH*120; i += 256) {
        int yl = i / 120, z = i - yl*120;
        int tyA[2], lyA[2]; int ny = halo_pairs(y0 + yl, tyA, lyA);
        int tzA[2], lzA[2]; int nz = halo_pairs(z, tzA, lzA);
        float s = 0.f;
        for (int ii=0; ii<nx; ++ii)
            for (int jj=0; jj<ny; ++jj)
                for (int kk=0; kk<nz; ++kk) {
                    int tile = (txA[ii]*NTPD + tyA[jj])*NTPD + tzA[kk];
                    int cell = (lxA[ii]*FP + lyA[jj])*FP + lzA[kk];
                    s += buf[(size_t)tile*FPSTRIDE + cell];
                }
        lin[yl][z] = s;
    }
    __syncthreads();
    // radix-8 combine: z = 15m + j ; Y[r][j] = sum_m x W8^{rm}
    for (int t = threadIdx.x; t < YCH*15; t += 256) {
        int yl = t / 15, j = t - (t/15)*15;
        float2 xin[8], Yo[8];
        #pragma unroll
        for (int m=0;m<8;++m) xin[m] = make_float2(lin[yl][15*m+j], 0.f);
        dft8(xin, Yo);
        #pragma unroll
        for (int r=0;r<8;++r) Ys[yl][r*17+j] = Yo[r];
    }
    __syncthreads();
    for (int o = threadIdx.x; o < YCH*NKZ; o += 256) {
        int kz = o / YCH, yl = o - (o/YCH)*YCH;
        const float2* Yp = &Ys[yl][(kz&7)*17];
        DFT15_BODY(Yp, kz, re, im)
        C1[(x*NKZ + kz)*120 + y0 + yl] = make_float2(re, im);
    }
}

// stage 2: cfft along y (radix-8). block = (4 consecutive x, kz). out C2[kz][ky][x].
__global__ void __launch_bounds__(256)
fft_y_kernel(const float2* __restrict__ C1,
             float2* __restrict__ C2) {
    int xc = blockIdx.x / NKZ;
    int kz = blockIdx.x - xc*NKZ;
    int x0 = xc * XCH;
    __shared__ float2 lin[XCH][121];
    __shared__ float2 Ys[XCH][YROW];
    for (int i = threadIdx.x; i < XCH*120; i += 256) {
        int xo = i / 120, y = i - (i/120)*120;
        lin[xo][y] = C1[((x0+xo)*NKZ + kz)*120 + y];
    }
    __syncthreads();
    for (int t = threadIdx.x; t < XCH*15; t += 256) {
        int xo = t / 15, j = t - (t/15)*15;
        float2 xin[8], Yo[8];
        #pragma unroll
        for (int m=0;m<8;++m) xin[m] = lin[xo][15*m+j];
        dft8(xin, Yo);
        #pragma unroll
        for (int r=0;r<8;++r) Ys[xo][r*17+j] = Yo[r];
    }
    __syncthreads();
    for (int o = threadIdx.x; o < XCH*120; o += 256) {
        int ky = o >> 2, xo = o & 3;
        const float2* Yp = &Ys[xo][(ky&7)*17];
        DFT15_BODY(Yp, ky, re, im)
        C2[(kz*120 + ky)*120 + x0 + xo] = make_float2(re, im);
    }
}

// stage 3: cfft along x (radix-8) + G-weighted energy (slotted atomic).
__global__ void __launch_bounds__(256)
fft_x_energy_kernel(const float2* __restrict__ C2,
                    const float* __restrict__ box,
                    double* __restrict__ ekslots) {
    int kyc = blockIdx.x / NKZ;
    int kz  = blockIdx.x - kyc*NKZ;
    int ky0 = kyc * XCH;
    __shared__ float2 lin[XCH][121];
    __shared__ float2 Ys[XCH][YROW];
    const float2* src = C2 + (kz*120 + ky0)*120;
    for (int i = threadIdx.x; i < XCH*120; i += 256) {
        int kyo = i / 120, xx = i - (i/120)*120;
        lin[kyo][xx] = src[i];
    }
    __syncthreads();
    for (int t = threadIdx.x; t < XCH*15; t += 256) {
        int kyo = t / 15, j = t - (t/15)*15;
        float2 xin[8], Yo[8];
        #pragma unroll
        for (int m=0;m<8;++m) xin[m] = lin[kyo][15*m+j];
        dft8(xin, Yo);
        #pragma unroll
        for (int r=0;r<8;++r) Ys[kyo][r*17+j] = Yo[r];
    }
    __syncthreads();
    float ib[9]; inv3(box, ib);
    const float TWOPI = 6.283185307179586f;
    float wzf = (kz==0 || kz==60) ? 1.0f : 2.0f;
    float contrib = 0.f;
    for (int o = threadIdx.x; o < XCH*120; o += 256) {
        int kyo = o / 120, kx = o - (o/120)*120;
        int ky = ky0 + kyo;
        const float2* Yp = &Ys[kyo][(kx&7)*17];
        DFT15_BODY(Yp, kx, re, im)
        if (!(kx==0 && ky==0 && kz==0)) {
            float mx = (kx < 60) ? (float)kx : (float)(kx - 120);
            float my = (ky < 60) ? (float)ky : (float)(ky - 120);
            float mz = (float)kz;
            float k0 = TWOPI*(mx*ib[0] + my*ib[1] + mz*ib[2]);
            float k1 = TWOPI*(mx*ib[3] + my*ib[4] + mz*ib[5]);
            float k2 = TWOPI*(mx*ib[6] + my*ib[7] + mz*ib[8]);
            float ksq = k0*k0 + k1*k1 + k2*k2;
            float G = 12.566370614359172f * __expf(-0.5f*(float)(ALPHA_C*ALPHA_C)*ksq) / ksq;
            contrib += wzf * G * (re*re + im*im);
        }
    }
    #pragma unroll
    for (int o=32;o>0;o>>=1) contrib += __shfl_down(contrib,o,64);
    __shared__ float sm[4];
    int lane = threadIdx.x & 63, w = threadIdx.x >> 6;
    if (lane==0) sm[w] = contrib;
    __syncthreads();
    if (threadIdx.x==0)
        atomicAdd(&ekslots[(blockIdx.x & (NSLOT-1)) * SLOTSTRIDE],
                  (double)(sm[0]+sm[1]+sm[2]+sm[3]));
}

// 64-lane slot reduction + closed-form corrections
__global__ void finalize_kernel(const double* __restrict__ ekslots,
                                const double* __restrict__ qslots,
                                const double* __restrict__ q2slots,
                                const float* __restrict__ box,
                                float* __restrict__ out) {
    int lane = threadIdx.x;
    double ek  = ekslots[lane*SLOTSTRIDE];
    double sq  = qslots [lane*SLOTSTRIDE];
    double sq2 = q2slots[lane*SLOTSTRIDE];
    #pragma unroll
    for (int o=32;o>0;o>>=1) {
        ek  += __shfl_down(ek,  o, 64);
        sq  += __shfl_down(sq,  o, 64);
        sq2 += __shfl_down(sq2, o, 64);
    }
    if (lane == 0) {
        double a00=box[0],a01=box[1],a02=box[2],a10=box[3],a11=box[4],a12=box[5],a20=box[6],a21=box[7],a22=box[8];
        double det = a00*(a11*a22-a12*a21) - a01*(a10*a22-a12*a20) + a02*(a10*a21-a11*a20);
        double vol = fabs(det);
        double E = ek/(2.0*vol)
                 - 0.5*sqrt(2.0/M_PI)/ALPHA_C * sq2
                 - M_PI*ALPHA_C*ALPHA_C * sq*sq / vol;
        out[0] = (float)E;
    }
}

extern "C" void kernel_launch(void* const* d_in, const int* in_sizes, int n_in,
                              void* d_out, int out_size, void* d_ws, size_t ws_size,
                              hipStream_t stream) {
    const float* coords  = (const float*)d_in[0];
    const float* box     = (const float*)d_in[1];
    const float* charges = (const float*)d_in[2];
    int n = in_sizes[0] / 3;

    char* ws = (char*)d_ws;
    double* ekslots = (double*)(ws + EK_OFF);
    double* qslots  = (double*)(ws + Q_OFF);
    double* q2slots = (double*)(ws + Q2_OFF);
    float*  buf     = (float*) (ws + BUF_OFF);
    float2* C1      = (float2*)(ws + C1_OFF);
    float2* C2      = (float2*)(ws + C2_OFF);
    int* counts     = (int*)(ws + COUNTS_OFF);
    float4* sorted  = (float4*)(ws + SORTED_OFF);

    int gA = (n + 255)/256;
    init_kernel<<<1, 1024, 0, stream>>>(counts, ekslots);
    scatter_q_kernel<<<gA, 256, 0, stream>>>(coords, box, charges, counts, sorted, qslots, q2slots, n);
    spread_tile_kernel<<<NTILE, 320, 0, stream>>>(sorted, counts, buf);
    fft_z_kernel<<<120*10, 256, 0, stream>>>(buf, C1);
    fft_y_kernel<<<30*NKZ, 256, 0, stream>>>(C1, C2);
    fft_x_energy_kernel<<<NKZ*30, 256, 0, stream>>>(C2, box, ekslots);
    finalize_kernel<<<1, 64, 0, stream>>>(ekslots, qslots, q2slots, box, (float*)d_out);
}

// Round 5
// 147.693 us; speedup vs baseline: 1.7328x; 1.0519x over previous
//
#include <hip/hip_runtime.h>
#include <math.h>

#define NMESH 120
#define NKZ 61            // rfft half-spectrum along z
#define ALPHA_C 1.0

#define TILE 12           // mesh cells per tile per dim
#define NTPD 10           // tiles per dim
#define NTILE 1000
#define FP 17             // footprint per dim: TILE + 5
#define FPCELLS (FP*FP*FP)   // 4913
#define FPSTRIDE 4928        // padded tile stride (buf layout)
#define CAP 256              // bucket capacity (Poisson(100): overflow ~1e-40)

#define CHUNK 128            // atoms staged per pass (P(cnt>128) ~ 0.3%)
// spread smem layout (floats)
#define WXA_OFF 0                    // [CHUNK][17] zero-padded wx
#define WYA_OFF (CHUNK*17)           // [CHUNK][17]
#define WZA_OFF (2*CHUNK*17)         // [CHUNK][20] stride 20 -> 16B aligned rows
#define LXS_OFF (2*CHUNK*17 + CHUNK*20)  // int[CHUNK]
#define SMEMF   (LXS_OFF + CHUNK)    // 7040 floats = 28160 B

#define YCH 12            // y-lines per fft_z block (1200 blocks)
#define XCH 4             // x per fft_y block / ky per fft_x block
#define YROW 137          // per-line Y storage: 8 rows * 17 + 1 pad (float2)

#define NSLOT 64          // accumulator slots (64B apart)
#define SLOTSTRIDE 8      // doubles per slot
#define W120C (-0.052359877559829887f)   // -2*pi/120

// ---- workspace layout (bytes) ----
// [0, 4096)      : double ekslots[64*8]
// [4096, 8192)   : double qslots [64*8]
// [8192, 12288)  : double q2slots[64*8]
// [115264, +19712000)  : float buf[1000][4928] tile footprints
// [19827264, +7027200) : float2 C1[x][kz][y]
//    counts + CAP-padded sorted atoms ALIAS the C1 region (dead before fft_z writes C1)
// C2[kz][ky][x] ALIASES buf (buf dead after fft_z)
#define EK_OFF      0
#define Q_OFF       4096
#define Q2_OFF      8192
#define BUF_OFF     115264
#define C1_OFF      19827264
#define C2_OFF      115264
#define COUNTS_OFF  C1_OFF
#define SORTED_OFF  (C1_OFF + 4096)

__device__ inline void inv3(const float* b, float* ib) {
    float a00=b[0],a01=b[1],a02=b[2],a10=b[3],a11=b[4],a12=b[5],a20=b[6],a21=b[7],a22=b[8];
    float c00 =  a11*a22 - a12*a21;
    float c01 = -(a10*a22 - a12*a20);
    float c02 =  a10*a21 - a11*a20;
    float c10 = -(a01*a22 - a02*a21);
    float c11 =  a00*a22 - a02*a20;
    float c12 = -(a00*a21 - a01*a20);
    float c20 =  a01*a12 - a02*a11;
    float c21 = -(a00*a12 - a02*a10);
    float c22 =  a00*a11 - a01*a10;
    float det = a00*c00 + a01*c01 + a02*c02;
    float inv = 1.0f/det;
    ib[0]=c00*inv; ib[1]=c10*inv; ib[2]=c20*inv;
    ib[3]=c01*inv; ib[4]=c11*inv; ib[5]=c21*inv;
    ib[6]=c02*inv; ib[7]=c12*inv; ib[8]=c22*inv;
}

__device__ inline void atom_pos(const float* __restrict__ box, float c0, float c1, float c2,
                                float* p) {
    float ib[9]; inv3(box, ib);
    #pragma unroll
    for (int d=0; d<3; ++d)
        p[d] = (c0*ib[0+d] + c1*ib[3+d] + c2*ib[6+d]) * 120.0f;
}

__device__ inline int wrap120(int i) { return ((i % 120) + 120) % 120; }

// order-6 Lagrange weights; x = pos - (floor(pos)+0.5)
__device__ inline void lag6(float x, float* w) {
    float df[6];
    #pragma unroll
    for (int k=0;k<6;++k) df[k] = x - ((float)k - 2.5f);
    w[0] = df[1]*df[2]*df[3]*df[4]*df[5] * (-1.0f/120.0f);
    w[1] = df[0]*df[2]*df[3]*df[4]*df[5] * ( 1.0f/24.0f);
    w[2] = df[0]*df[1]*df[3]*df[4]*df[5] * (-1.0f/12.0f);
    w[3] = df[0]*df[1]*df[2]*df[4]*df[5] * ( 1.0f/12.0f);
    w[4] = df[0]*df[1]*df[2]*df[3]*df[5] * (-1.0f/24.0f);
    w[5] = df[0]*df[1]*df[2]*df[3]*df[4] * ( 1.0f/120.0f);
}

// per-dim halo decomposition: cell c -> up to 2 (tile, local) pairs
__device__ inline int halo_pairs(int c, int* t, int* l) {
    int r = c % 12, ti = c / 12, n = 0;
    t[n] = ti;          l[n] = r + 2;  n++;
    if (r < 3)  { t[n] = (ti+9)%10; l[n] = r + 14; n++; }
    if (r >= 10){ t[n] = (ti+1)%10; l[n] = r - 10; n++; }
    return n;
}

// 8-point DFT, complex in (m-order), complex out (k-order). W8 = e^{-2pi i/8}.
__device__ inline void dft8(const float2* xin, float2* Y) {
    const float S = 0.70710678118654752f;
    float2 a=xin[0], b=xin[2], c=xin[4], d=xin[6];
    float s02r=a.x+c.x, s02i=a.y+c.y, d02r=a.x-c.x, d02i=a.y-c.y;
    float s13r=b.x+d.x, s13i=b.y+d.y, d13r=b.x-d.x, d13i=b.y-d.y;
    float2 E0 = make_float2(s02r+s13r, s02i+s13i);
    float2 E1 = make_float2(d02r+d13i, d02i-d13r);   // d02 - i*d13
    float2 E2 = make_float2(s02r-s13r, s02i-s13i);
    float2 E3 = make_float2(d02r-d13i, d02i+d13r);
    a=xin[1]; b=xin[3]; c=xin[5]; d=xin[7];
    s02r=a.x+c.x; s02i=a.y+c.y; d02r=a.x-c.x; d02i=a.y-c.y;
    s13r=b.x+d.x; s13i=b.y+d.y; d13r=b.x-d.x; d13i=b.y-d.y;
    float2 O0 = make_float2(s02r+s13r, s02i+s13i);
    float2 O1 = make_float2(d02r+d13i, d02i-d13r);
    float2 O2 = make_float2(s02r-s13r, s02i-s13i);
    float2 O3 = make_float2(d02r-d13i, d02i+d13r);
    float t1r = S*(O1.x + O1.y), t1i = S*(O1.y - O1.x);   // W8^1 * O1
    float t2r = O2.y,            t2i = -O2.x;             // W8^2 = -i
    float t3r = S*(O3.y - O3.x), t3i = -S*(O3.x + O3.y);  // W8^3
    Y[0] = make_float2(E0.x + O0.x, E0.y + O0.y);
    Y[4] = make_float2(E0.x - O0.x, E0.y - O0.y);
    Y[1] = make_float2(E1.x + t1r,  E1.y + t1i);
    Y[5] = make_float2(E1.x - t1r,  E1.y - t1i);
    Y[2] = make_float2(E2.x + t2r,  E2.y + t2i);
    Y[6] = make_float2(E2.x - t2r,  E2.y - t2i);
    Y[3] = make_float2(E3.x + t3r,  E3.y + t3i);
    Y[7] = make_float2(E3.x - t3r,  E3.y - t3i);
}

__global__ void init_kernel(int* __restrict__ counts, double* __restrict__ slots) {
    int idx = threadIdx.x;
    for (int i = idx; i < 3*NSLOT*SLOTSTRIDE; i += 1024) slots[i] = 0.0;
    for (int i = idx; i < NTILE; i += 1024) counts[i] = 0;
}

// one-pass bucket scatter + sum(q) + sum(q^2) into per-slot accumulators
__global__ void scatter_q_kernel(const float* __restrict__ coords,
                                 const float* __restrict__ box,
                                 const float* __restrict__ charges,
                                 int* __restrict__ counts,
                                 float4* __restrict__ sorted,
                                 double* __restrict__ qslots,
                                 double* __restrict__ q2slots, int n) {
    int i = blockIdx.x*blockDim.x + threadIdx.x;
    float v = 0.f, v2 = 0.f;
    if (i < n) {
        float p[3]; atom_pos(box, coords[3*i], coords[3*i+1], coords[3*i+2], p);
        float q = charges[i];
        v = q; v2 = q*q;
        int t[3];
        #pragma unroll
        for (int d=0; d<3; ++d) t[d] = wrap120((int)floorf(p[d])) / TILE;
        int tile = (t[0]*NTPD + t[1])*NTPD + t[2];
        int idx = atomicAdd(&counts[tile], 1);
        if (idx < CAP) sorted[tile*CAP + idx] = make_float4(p[0], p[1], p[2], q);
    }
    #pragma unroll
    for (int o=32;o>0;o>>=1) { v += __shfl_down(v,o,64); v2 += __shfl_down(v2,o,64); }
    __shared__ float s1[4], s2[4];
    int lane = threadIdx.x & 63, w = threadIdx.x >> 6;
    if (lane==0) { s1[w]=v; s2[w]=v2; }
    __syncthreads();
    if (threadIdx.x==0) {
        for (int j=1;j<4;j++) { v += s1[j]; v2 += s2[j]; }
        int slot = (blockIdx.x & (NSLOT-1)) * SLOTSTRIDE;
        atomicAdd(&qslots[slot],  (double)v);
        atomicAdd(&q2slots[slot], (double)v2);
    }
}

// Register z-column spread (round-3 verified structure).
// Round-5 deltas: (a) ballot-compacted atom loop (iterate only set bits
// instead of 128x readlane+branch), (b) wza rows zeroed via float4
// (5 stores vs 20 scalar at 8-way bank conflict). No cooperative anything.
__global__ void __launch_bounds__(320)
spread_tile_kernel(const float4* __restrict__ sorted,
                   const int* __restrict__ counts,
                   float* __restrict__ buf) {
    int tile = blockIdx.x;
    int tx = tile / (NTPD*NTPD);
    int rem = tile - tx*NTPD*NTPD;
    int ty = rem / NTPD;
    int tz = rem - ty*NTPD;
    int bx = tx*TILE, by = ty*TILE, bz = tz*TILE;

    __shared__ float smem[SMEMF];
    int* lxs = (int*)&smem[LXS_OFF];

    int tid = threadIdx.x;
    int A = tid / 17, B = tid - A*17;
    int Ac = (A > 16) ? 16 : A;        // clamp: tail threads read in-bounds garbage
    int wv = tid >> 6, lane = tid & 63;
    int Alo = (wv*64)/17;
    int Ahi = (wv*64+63)/17; if (Ahi > 16) Ahi = 16;

    float acc[17];
    #pragma unroll
    for (int k=0;k<17;++k) acc[k] = 0.f;

    int cntT = min(counts[tile], CAP);
    const float4* src = sorted + (size_t)tile*CAP;

    for (int start = 0; start < cntT; start += CHUNK) {
        int jn = cntT - start; if (jn > CHUNK) jn = CHUNK;
        __syncthreads();                 // prev-chunk readers done
        if (tid < jn) {
            float4 s = src[start + tid];
            float fx = floorf(s.x), fy = floorf(s.y), fz = floorf(s.z);
            float wx[6]; lag6(s.x - (fx + 0.5f), wx);
            float wy[6]; lag6(s.y - (fy + 0.5f), wy);
            float wz[6]; lag6(s.z - (fz + 0.5f), wz);
            int lx = wrap120((int)fx) - bx;
            int ly = wrap120((int)fy) - by;
            int lz = wrap120((int)fz) - bz;
            #pragma unroll
            for (int k=0;k<17;++k) { smem[WXA_OFF + tid*17 + k] = 0.f;
                                     smem[WYA_OFF + tid*17 + k] = 0.f; }
            float4* wzp = (float4*)&smem[WZA_OFF + tid*20];
            float4 zz4 = make_float4(0.f,0.f,0.f,0.f);
            #pragma unroll
            for (int k=0;k<5;++k) wzp[k] = zz4;
            #pragma unroll
            for (int k=0;k<6;++k) {
                smem[WXA_OFF + tid*17 + lx + k] = wx[k];
                smem[WYA_OFF + tid*17 + ly + k] = wy[k];
                smem[WZA_OFF + tid*20 + lz + k] = wz[k]*s.w;
            }
            lxs[tid] = lx;
        }
        __syncthreads();
        int l0 = lxs[lane], l1 = lxs[64+lane];
        bool g0 = (lane < jn)    && (l0 <= Ahi) && (l0 + 5 >= Alo);
        bool g1 = (64+lane < jn) && (l1 <= Ahi) && (l1 + 5 >= Alo);
        unsigned long long m0 = __ballot(g0);
        unsigned long long m1 = __ballot(g1);
        auto body = [&](int j) {
            float wx_ = smem[WXA_OFF + j*17 + Ac];
            float wy_ = smem[WYA_OFF + j*17 + B];
            float w2 = wx_ * wy_;
            const float4* zp = (const float4*)&smem[WZA_OFF + j*20];
            float4 z0 = zp[0], z1 = zp[1], z2 = zp[2], z3 = zp[3];
            float z16 = smem[WZA_OFF + j*20 + 16];
            acc[0] = fmaf(w2,z0.x,acc[0]);  acc[1] = fmaf(w2,z0.y,acc[1]);
            acc[2] = fmaf(w2,z0.z,acc[2]);  acc[3] = fmaf(w2,z0.w,acc[3]);
            acc[4] = fmaf(w2,z1.x,acc[4]);  acc[5] = fmaf(w2,z1.y,acc[5]);
            acc[6] = fmaf(w2,z1.z,acc[6]);  acc[7] = fmaf(w2,z1.w,acc[7]);
            acc[8] = fmaf(w2,z2.x,acc[8]);  acc[9] = fmaf(w2,z2.y,acc[9]);
            acc[10]= fmaf(w2,z2.z,acc[10]); acc[11]= fmaf(w2,z2.w,acc[11]);
            acc[12]= fmaf(w2,z3.x,acc[12]); acc[13]= fmaf(w2,z3.y,acc[13]);
            acc[14]= fmaf(w2,z3.z,acc[14]); acc[15]= fmaf(w2,z3.w,acc[15]);
            acc[16]= fmaf(w2,z16, acc[16]);
        };
        while (m0) { int j = __builtin_ctzll(m0); m0 &= m0-1ull; body(j); }
        while (m1) { int j = 64 + __builtin_ctzll(m1); m1 &= m1-1ull; body(j); }
    }
    __syncthreads();
    // overlay: registers -> flat LDS footprint (index (A*17+B)*17+k == tid*17+k)
    if (tid < 289) {
        #pragma unroll
        for (int k=0;k<17;++k) smem[tid*17 + k] = acc[k];
    }
    __syncthreads();
    for (int i = tid; i < FPCELLS; i += 320)
        buf[(size_t)tile * FPSTRIDE + i] = smem[i];
}

// ---- radix-8 decimated 120-point DFT inner loop ----
// X[k] = sum_{j<15} Y[k&7][j] * W120^{k*j};  3 strands (j mod 3) for ILP.
// w1 twiddle from per-block LDS table (one sincos per k per block, not per output).
#define DFT15_BODY(Yp, kfreq, RE, IM)                                        \
    float w1r = tw[kfreq].x, w1i = tw[kfreq].y;                              \
    float w2r = w1r*w1r - w1i*w1i, w2i = 2.f*w1r*w1i;                        \
    float w3r = w2r*w1r - w2i*w1i, w3i = w2r*w1i + w2i*w1r;                  \
    float ar=1.f, ai=0.f, br=w1r, bi=w1i, cr=w2r, ci=w2i;                    \
    float r0_=0.f,i0_=0.f,r1_=0.f,i1_=0.f,r2_=0.f,i2_=0.f;                   \
    _Pragma("unroll")                                                        \
    for (int s_=0;s_<5;++s_) {                                               \
        float2 ya = (Yp)[3*s_], yb = (Yp)[3*s_+1], yc = (Yp)[3*s_+2];        \
        r0_ = fmaf(ya.x, ar, fmaf(-ya.y, ai, r0_));                          \
        i0_ = fmaf(ya.x, ai, fmaf( ya.y, ar, i0_));                          \
        r1_ = fmaf(yb.x, br, fmaf(-yb.y, bi, r1_));                          \
        i1_ = fmaf(yb.x, bi, fmaf( yb.y, br, i1_));                          \
        r2_ = fmaf(yc.x, cr, fmaf(-yc.y, ci, r2_));                          \
        i2_ = fmaf(yc.x, ci, fmaf( yc.y, cr, i2_));                          \
        float n_;                                                            \
        n_ = ar*w3r - ai*w3i; ai = ar*w3i + ai*w3r; ar = n_;                 \
        n_ = br*w3r - bi*w3i; bi = br*w3i + bi*w3r; br = n_;                 \
        n_ = cr*w3r - ci*w3i; ci = cr*w3i + ci*w3r; cr = n_;                 \
    }                                                                        \
    float RE = (r0_+r1_)+r2_, IM = (i0_+i1_)+i2_;

#define TWIDDLE_INIT()                                                       \
    __shared__ float2 tw[120];                                               \
    for (int k_ = threadIdx.x; k_ < 120; k_ += blockDim.x) {                 \
        float s_, c_; __sincosf(W120C * (float)k_, &s_, &c_);                \
        tw[k_] = make_float2(c_, s_);                                        \
    }

// stage 1: halo-gather + rfft along z (radix-8 pre-combine). out C1[x][kz][y].
__global__ void __launch_bounds__(256)
fft_z_kernel(const float* __restrict__ buf,
             float2* __restrict__ C1) {
    int x  = blockIdx.x / 10;
    int y0 = (blockIdx.x - x*10) * YCH;
    __shared__ float  lin[YCH][121];
    __shared__ float2 Ys[YCH][YROW];    // per line: 8 rows * 17 (+1 pad)
    TWIDDLE_INIT()

    int txA[2], lxA[2];
    int nx = halo_pairs(x, txA, lxA);

    for (int i = threadIdx.x; i < YCH*120; i += 256) {
        int yl = i / 120, z = i - yl*120;
        int tyA[2], lyA[2]; int ny = halo_pairs(y0 + yl, tyA, lyA);
        int tzA[2], lzA[2]; int nz = halo_pairs(z, tzA, lzA);
        float s = 0.f;
        for (int ii=0; ii<nx; ++ii)
            for (int jj=0; jj<ny; ++jj)
                for (int kk=0; kk<nz; ++kk) {
                    int tile = (txA[ii]*NTPD + tyA[jj])*NTPD + tzA[kk];
                    int cell = (lxA[ii]*FP + lyA[jj])*FP + lzA[kk];
                    s += buf[(size_t)tile*FPSTRIDE + cell];
                }
        lin[yl][z] = s;
    }
    __syncthreads();
    // radix-8 combine: z = 15m + j ; Y[r][j] = sum_m x W8^{rm}
    for (int t = threadIdx.x; t < YCH*15; t += 256) {
        int yl = t / 15, j = t - (t/15)*15;
        float2 xin[8], Yo[8];
        #pragma unroll
        for (int m=0;m<8;++m) xin[m] = make_float2(lin[yl][15*m+j], 0.f);
        dft8(xin, Yo);
        #pragma unroll
        for (int r=0;r<8;++r) Ys[yl][r*17+j] = Yo[r];
    }
    __syncthreads();
    for (int o = threadIdx.x; o < YCH*NKZ; o += 256) {
        int kz = o / YCH, yl = o - (o/YCH)*YCH;
        const float2* Yp = &Ys[yl][(kz&7)*17];
        DFT15_BODY(Yp, kz, re, im)
        C1[(x*NKZ + kz)*120 + y0 + yl] = make_float2(re, im);
    }
}

// stage 2: cfft along y (radix-8). block = (4 consecutive x, kz). out C2[kz][ky][x].
__global__ void __launch_bounds__(256)
fft_y_kernel(const float2* __restrict__ C1,
             float2* __restrict__ C2) {
    int xc = blockIdx.x / NKZ;
    int kz = blockIdx.x - xc*NKZ;
    int x0 = xc * XCH;
    __shared__ float2 lin[XCH][121];
    __shared__ float2 Ys[XCH][YROW];
    TWIDDLE_INIT()
    for (int i = threadIdx.x; i < XCH*120; i += 256) {
        int xo = i / 120, y = i - (i/120)*120;
        lin[xo][y] = C1[((x0+xo)*NKZ + kz)*120 + y];
    }
    __syncthreads();
    for (int t = threadIdx.x; t < XCH*15; t += 256) {
        int xo = t / 15, j = t - (t/15)*15;
        float2 xin[8], Yo[8];
        #pragma unroll
        for (int m=0;m<8;++m) xin[m] = lin[xo][15*m+j];
        dft8(xin, Yo);
        #pragma unroll
        for (int r=0;r<8;++r) Ys[xo][r*17+j] = Yo[r];
    }
    __syncthreads();
    for (int o = threadIdx.x; o < XCH*120; o += 256) {
        int ky = o >> 2, xo = o & 3;
        const float2* Yp = &Ys[xo][(ky&7)*17];
        DFT15_BODY(Yp, ky, re, im)
        C2[(kz*120 + ky)*120 + x0 + xo] = make_float2(re, im);
    }
}

// stage 3: cfft along x (radix-8) + G-weighted energy (slotted atomic).
__global__ void __launch_bounds__(256)
fft_x_energy_kernel(const float2* __restrict__ C2,
                    const float* __restrict__ box,
                    double* __restrict__ ekslots) {
    int kyc = blockIdx.x / NKZ;
    int kz  = blockIdx.x - kyc*NKZ;
    int ky0 = kyc * XCH;
    __shared__ float2 lin[XCH][121];
    __shared__ float2 Ys[XCH][YROW];
    TWIDDLE_INIT()
    const float2* src = C2 + (kz*120 + ky0)*120;
    for (int i = threadIdx.x; i < XCH*120; i += 256) {
        int kyo = i / 120, xx = i - (i/120)*120;
        lin[kyo][xx] = src[i];
    }
    __syncthreads();
    for (int t = threadIdx.x; t < XCH*15; t += 256) {
        int kyo = t / 15, j = t - (t/15)*15;
        float2 xin[8], Yo[8];
        #pragma unroll
        for (int m=0;m<8;++m) xin[m] = lin[kyo][15*m+j];
        dft8(xin, Yo);
        #pragma unroll
        for (int r=0;r<8;++r) Ys[kyo][r*17+j] = Yo[r];
    }
    __syncthreads();
    float ib[9]; inv3(box, ib);
    const float TWOPI = 6.283185307179586f;
    float wzf = (kz==0 || kz==60) ? 1.0f : 2.0f;
    float contrib = 0.f;
    for (int o = threadIdx.x; o < XCH*120; o += 256) {
        int kyo = o / 120, kx = o - (o/120)*120;
        int ky = ky0 + kyo;
        const float2* Yp = &Ys[kyo][(kx&7)*17];
        DFT15_BODY(Yp, kx, re, im)
        if (!(kx==0 && ky==0 && kz==0)) {
            float mx = (kx < 60) ? (float)kx : (float)(kx - 120);
            float my = (ky < 60) ? (float)ky : (float)(ky - 120);
            float mz = (float)kz;
            float k0 = TWOPI*(mx*ib[0] + my*ib[1] + mz*ib[2]);
            float k1 = TWOPI*(mx*ib[3] + my*ib[4] + mz*ib[5]);
            float k2 = TWOPI*(mx*ib[6] + my*ib[7] + mz*ib[8]);
            float ksq = k0*k0 + k1*k1 + k2*k2;
            float G = 12.566370614359172f * __expf(-0.5f*(float)(ALPHA_C*ALPHA_C)*ksq) / ksq;
            contrib += wzf * G * (re*re + im*im);
        }
    }
    #pragma unroll
    for (int o=32;o>0;o>>=1) contrib += __shfl_down(contrib,o,64);
    __shared__ float sm[4];
    int lane = threadIdx.x & 63, w = threadIdx.x >> 6;
    if (lane==0) sm[w] = contrib;
    __syncthreads();
    if (threadIdx.x==0)
        atomicAdd(&ekslots[(blockIdx.x & (NSLOT-1)) * SLOTSTRIDE],
                  (double)(sm[0]+sm[1]+sm[2]+sm[3]));
}

// 64-lane slot reduction + closed-form corrections
__global__ void finalize_kernel(const double* __restrict__ ekslots,
                                const double* __restrict__ qslots,
                                const double* __restrict__ q2slots,
                                const float* __restrict__ box,
                                float* __restrict__ out) {
    int lane = threadIdx.x;
    double ek  = ekslots[lane*SLOTSTRIDE];
    double sq  = qslots [lane*SLOTSTRIDE];
    double sq2 = q2slots[lane*SLOTSTRIDE];
    #pragma unroll
    for (int o=32;o>0;o>>=1) {
        ek  += __shfl_down(ek,  o, 64);
        sq  += __shfl_down(sq,  o, 64);
        sq2 += __shfl_down(sq2, o, 64);
    }
    if (lane == 0) {
        double a00=box[0],a01=box[1],a02=box[2],a10=box[3],a11=box[4],a12=box[5],a20=box[6],a21=box[7],a22=box[8];
        double det = a00*(a11*a22-a12*a21) - a01*(a10*a22-a12*a20) + a02*(a10*a21-a11*a20);
        double vol = fabs(det);
        double E = ek/(2.0*vol)
                 - 0.5*sqrt(2.0/M_PI)/ALPHA_C * sq2
                 - M_PI*ALPHA_C*ALPHA_C * sq*sq / vol;
        out[0] = (float)E;
    }
}

extern "C" void kernel_launch(void* const* d_in, const int* in_sizes, int n_in,
                              void* d_out, int out_size, void* d_ws, size_t ws_size,
                              hipStream_t stream) {
    const float* coords  = (const float*)d_in[0];
    const float* box     = (const float*)d_in[1];
    const float* charges = (const float*)d_in[2];
    int n = in_sizes[0] / 3;

    char* ws = (char*)d_ws;
    double* ekslots = (double*)(ws + EK_OFF);
    double* qslots  = (double*)(ws + Q_OFF);
    double* q2slots = (double*)(ws + Q2_OFF);
    float*  buf     = (float*) (ws + BUF_OFF);
    float2* C1      = (float2*)(ws + C1_OFF);
    float2* C2      = (float2*)(ws + C2_OFF);
    int* counts     = (int*)(ws + COUNTS_OFF);
    float4* sorted  = (float4*)(ws + SORTED_OFF);

    int gA = (n + 255)/256;
    init_kernel<<<1, 1024, 0, stream>>>(counts, ekslots);
    scatter_q_kernel<<<gA, 256, 0, stream>>>(coords, box, charges, counts, sorted, qslots, q2slots, n);
    spread_tile_kernel<<<NTILE, 320, 0, stream>>>(sorted, counts, buf);
    fft_z_kernel<<<120*10, 256, 0, stream>>>(buf, C1);
    fft_y_kernel<<<30*NKZ, 256, 0, stream>>>(C1, C2);
    fft_x_energy_kernel<<<NKZ*30, 256, 0, stream>>>(C2, box, ekslots);
    finalize_kernel<<<1, 64, 0, stream>>>(ekslots, qslots, q2slots, box, (float*)d_out);
}